// Round 7
// baseline (21028.470 us; speedup 1.0000x reference)
//
#include <hip/hip_runtime.h>
#include <hip/hip_bf16.h>
#include <math.h>

#define HIDN 400
#define KK   10
#define UU   64
#define DD   60
#define TT   600
#define BB   64
#define FCIN 800
#define FCOUT 121

#define PBLK 200      // persistent blocks (1 per CU via LDS; <= 256 CUs)
#define NWB  64       // window blocks 0..63 (one batch each)
#define NG2  100      // GEMV2 blocks 64..163 (4 hidden units each)
#define THR  1024     // 16 waves
#define NWAVE 16
#define CB1  8        // GEMV1 cols per block (2 units x 4 gates)
#define CB2  16       // GEMV2 cols per block (4 units x 4 gates)

#define SLOT1 25600   // 400*64
#define SLOTW 3840    // 60*64

// ---- d_out offsets (floats) ----
#define PI_OFF    0
#define MU_OFF    768000
#define SIG_OFF   2304000
#define RHO_OFF   3840000
#define EOS_OFF   4608000
#define WF_OFF    4646400
#define KAPPA_OFF 4650240
#define PHI_OFF   4650880
#define H0F_OFF   4654976
#define C0F_OFF   4680576
#define H1F_OFF   4706176
#define C1F_OFF   4731776

// ---- workspace offsets (floats) ----
#define WS_H1T   0                  // 601*25600
#define WS_H2T   15385600           // 601*25600
#define WS_WHT   30771200           // 601*3840
#define WS_XST   33079040           // 600*3*64
#define WS_WALL1 33194240           // 200*463*8
#define WS_WALL2 33935040           // 100*863*16 = 1,380,800
#define WS_WFCT  35315840           // 800*121
#define WS_CNT   35412640           // 5824 ints
// total ~= 35,418,464 floats = 141.7 MB

// ---- per-block epoch words (line-isolated, value = steps completed) ----
#define CAW(p)  ((p)*16)            // h1 epochs, 200 blocks
#define CHW(q)  (3200 + (q)*16)     // h2 epochs, 100 blocks
#define CWW(b)  (4800 + (b)*16)     // w  epochs, 64 blocks
#define CNT_INTS 5824

__device__ __forceinline__ float sigm(float x){ return 1.0f/(1.0f + expf(-x)); }

__device__ __forceinline__ void st_agent(float* p, float v){
  __hip_atomic_store(p, v, __ATOMIC_RELAXED, __HIP_MEMORY_SCOPE_AGENT);
}
__device__ __forceinline__ void st_agent_i(int* p, int v){
  __hip_atomic_store(p, v, __ATOMIC_RELAXED, __HIP_MEMORY_SCOPE_AGENT);
}
__device__ __forceinline__ int ld_agent_i(const int* p){
  return __hip_atomic_load(p, __ATOMIC_RELAXED, __HIP_MEMORY_SCOPE_AGENT);
}
__device__ __forceinline__ void spin_ge(const int* w, int tgt){
  if (ld_agent_i(w) >= tgt) return;
  do { __builtin_amdgcn_s_sleep(1); } while (ld_agent_i(w) < tgt);
}

// ---------- prep ----------
__global__ void prep_init(const float* __restrict__ onehots, const float* __restrict__ strokes,
                          float* __restrict__ H1t, float* __restrict__ H2t,
                          float* __restrict__ Wh,  float* __restrict__ XST,
                          int* __restrict__ cnts){
  int idx = blockIdx.x*blockDim.x + threadIdx.x;
  if (idx < SLOT1){ H1t[idx] = 0.f; H2t[idx] = 0.f; }
  if (idx < SLOTW){
    int d = idx >> 6, b = idx & 63;
    Wh[idx] = onehots[b*(UU*DD) + d];            // onehots[b, u=0, d]
  }
  if (idx < TT*3*64){
    int t = idx/192, rem = idx%192, comp = rem/64, b = rem%64;
    XST[idx] = strokes[(b*TT + t)*3 + comp];
  }
  if (idx < CNT_INTS) cnts[idx] = 0;
}

// ---------- weight reorder ----------
// GEMV1: block p owns units {2p,2p+1}; col c = 2*q + (j&1); rows [0,400)=h1,[400,460)=w,[460,463)=x
// GEMV2: block q2 (=64+q2) owns units {4q2..4q2+3}; col c = 4*q + (j&3);
//        rows [0,400)=h1,[400,800)=h2,[800,860)=w,[860,863)=x
__global__ void prep_wall(const float* __restrict__ Wih1, const float* __restrict__ Whh1,
                          const float* __restrict__ Wih2, const float* __restrict__ Whh2,
                          float* __restrict__ WALL1, float* __restrict__ WALL2){
  int idx = blockIdx.x*blockDim.x + threadIdx.x;
  if (idx < 640000){                       // W_hh1 (1600,400)
    int g = idx/400, k = idx%400;
    int q = g/400, j = g%400, p = j>>1, c = 2*q + (j&1);
    WALL1[(p*463 + k)*CB1 + c] = Whh1[idx];
  } else if (idx < 740800){                // W_ih1 (1600,63)
    int s = idx - 640000;
    int g = s/63, col = s%63;
    int q = g/400, j = g%400, p = j>>1, c = 2*q + (j&1);
    int r = (col < 3) ? (460 + col) : (400 + col - 3);
    WALL1[(p*463 + r)*CB1 + c] = Wih1[s];
  } else if (idx < 1380800){               // W_hh2 (1600,400)
    int s = idx - 740800;
    int g = s/400, k = s%400;
    int q = g/400, j = g%400, q2 = j>>2, c = 4*q + (j&3);
    WALL2[((size_t)q2*863 + 400 + k)*CB2 + c] = Whh2[s];
  } else if (idx < 2121600){               // W_ih2 (1600,463)
    int s = idx - 1380800;
    int g = s/463, col = s%463;
    int q = g/400, j = g%400, q2 = j>>2, c = 4*q + (j&3);
    int r = (col<3) ? (860+col) : (col<63 ? (800+col-3) : (col-63));
    WALL2[((size_t)q2*863 + r)*CB2 + c] = Wih2[s];
  }
}

__global__ void prep_wfc(const float* __restrict__ Wfc, float* __restrict__ WfcT){
  int idx = blockIdx.x*blockDim.x + threadIdx.x;
  if (idx >= FCIN*FCOUT) return;
  int k = idx / FCOUT, j = idx - k*FCOUT;
  WfcT[idx] = Wfc[j*FCIN + k];
}

// ---------- GEMV segments ----------
__device__ __forceinline__ void gemv_seg(const float* __restrict__ x,
                                         const float* __restrict__ w,
                                         int n, int bg4, int cg2, float acc[8]){
  #pragma unroll 8
  for (int k=0;k<n;++k){
    const float4 xv = *(const float4*)(x + k*64 + bg4);
    const float2 wv = *(const float2*)(w + k*CB1 + cg2);
    acc[0] = fmaf(wv.x, xv.x, acc[0]);
    acc[1] = fmaf(wv.x, xv.y, acc[1]);
    acc[2] = fmaf(wv.x, xv.z, acc[2]);
    acc[3] = fmaf(wv.x, xv.w, acc[3]);
    acc[4] = fmaf(wv.y, xv.x, acc[4]);
    acc[5] = fmaf(wv.y, xv.y, acc[5]);
    acc[6] = fmaf(wv.y, xv.z, acc[6]);
    acc[7] = fmaf(wv.y, xv.w, acc[7]);
  }
}
__device__ __forceinline__ void gemv_seg2(const float* __restrict__ x,
                                          const float* __restrict__ w,
                                          int n, int bg8, int cg2, float acc[16]){
  #pragma unroll 8
  for (int k=0;k<n;++k){
    const float4 xa = *(const float4*)(x + k*64 + bg8);
    const float4 xb = *(const float4*)(x + k*64 + bg8 + 4);
    const float2 wv = *(const float2*)(w + k*CB2 + cg2);
    acc[0]  = fmaf(wv.x, xa.x, acc[0]);
    acc[1]  = fmaf(wv.x, xa.y, acc[1]);
    acc[2]  = fmaf(wv.x, xa.z, acc[2]);
    acc[3]  = fmaf(wv.x, xa.w, acc[3]);
    acc[4]  = fmaf(wv.x, xb.x, acc[4]);
    acc[5]  = fmaf(wv.x, xb.y, acc[5]);
    acc[6]  = fmaf(wv.x, xb.z, acc[6]);
    acc[7]  = fmaf(wv.x, xb.w, acc[7]);
    acc[8]  = fmaf(wv.y, xa.x, acc[8]);
    acc[9]  = fmaf(wv.y, xa.y, acc[9]);
    acc[10] = fmaf(wv.y, xa.z, acc[10]);
    acc[11] = fmaf(wv.y, xa.w, acc[11]);
    acc[12] = fmaf(wv.y, xb.x, acc[12]);
    acc[13] = fmaf(wv.y, xb.y, acc[13]);
    acc[14] = fmaf(wv.y, xb.z, acc[14]);
    acc[15] = fmaf(wv.y, xb.w, acc[15]);
  }
}

// ---------- persistent recurrent kernel ----------
__global__ __launch_bounds__(THR) void recurrent_kernel(
    const float* __restrict__ Wwin, const float* __restrict__ bwin,
    const float* __restrict__ b1g,  const float* __restrict__ b2g,
    const float* __restrict__ tmask,const float* __restrict__ onehots,
    const float* __restrict__ WALL1,const float* __restrict__ WALL2,
    float* __restrict__ H1t,        float* __restrict__ H2t,
    float* __restrict__ Wh,         const float* __restrict__ XST,
    int* __restrict__ cnts,         float* __restrict__ outp)
{
  const int p    = blockIdx.x;
  const int tid  = threadIdx.x;
  const int wave = tid >> 6, lane = tid & 63;
  const int bg4  = (lane & 15) * 4;   // GEMV1: 4 batches
  const int cg2  = (lane >> 4) * 2;   // GEMV1: 2 cols
  const int bg8  = (lane & 7) * 8;    // GEMV2: 8 batches
  const int c2g2 = (lane >> 3) * 2;   // GEMV2: 2 cols
  const bool isWin = (p < NWB);
  const bool isG2  = (p >= NWB && p < NWB + NG2);

  // ---- overlaid LDS (154.7 KB) ----
  __shared__ float SMEM[38680];
  float* WL1S  = SMEM;            // 3704 (all)
  float* WL2S  = SMEM + 3704;     // 13808 (G2 blocks)
  float* WWINS = SMEM + 3704;     // 12000 (window blocks)
  float* ONEHS = SMEM + 15704;    // 3840  (window)
  float* TMSKS = SMEM + 19544;    // 64    (window)
  float* HBUFS = SMEM + 19608;    // 400   (window)
  float* PWS   = SMEM + 20008;    // 30    (window)
  float* KAPS  = SMEM + 20040;    // 10    (window)
  float* PHIS  = SMEM + 20056;    // 64    (window)
  float* PARTS = SMEM + 20864;    // 16384 (all; GEMV1 uses first 8192)
  float* GREDS = SMEM + 37248;    // 1024
  float* CS1S  = SMEM + 38272;    // 128
  float* CS2S  = SMEM + 38400;    // 256
  float* BS1S  = SMEM + 38656;    // 8
  float* BS2S  = SMEM + 38664;    // 16

  for (int idx = tid; idx < 463*CB1; idx += THR) WL1S[idx] = WALL1[p*463*CB1 + idx];
  if (isG2) for (int idx = tid; idx < 863*CB2; idx += THR) WL2S[idx] = WALL2[(size_t)(p-NWB)*863*CB2 + idx];
  if (tid < CB1){ int q = tid>>1, u = tid&1; int j = 2*p+u; BS1S[tid] = b1g[q*HIDN + j]; }
  if (isG2 && tid < CB2){ int q = tid>>2, uu = tid&3; int j = 4*(p-NWB)+uu; BS2S[tid] = b2g[q*HIDN + j]; }
  if (tid < 128) CS1S[tid] = 0.f;
  if (tid < 256) CS2S[tid] = 0.f;
  if (isWin){
    for (int idx = tid; idx < 30*400; idx += THR) WWINS[idx] = Wwin[idx];
    for (int idx = tid; idx < UU*DD;  idx += THR) ONEHS[idx] = onehots[p*(UU*DD) + idx];
    if (tid < UU) TMSKS[tid] = tmask[p*UU + tid];
    if (tid < KK) KAPS[tid] = 0.f;
  }
  __syncthreads();

  for (int i = 0; i <= TT; ++i){
    // ---- merged top wait: h1(i-1), w(i-1), h2(i-2) ----
    if (i >= 1){
      if (tid < PBLK)                        spin_ge(&cnts[CAW(tid)], i);
      else if (tid >= 256 && tid < 256+NG2){ if (i >= 2) spin_ge(&cnts[CHW(tid-256)], i-1); }
      else if (tid >= 384 && tid < 384+NWB)  spin_ge(&cnts[CWW(tid-384)], i);
      asm volatile("" ::: "memory");
      __syncthreads();
    }

    if (i < TT){
      // ---- GEMV1 step i: h1(i-1)[0,400), w(i-1)[400,460), x(i)[460,463) ----
      const float* __restrict__ H1prev = H1t + (size_t)i*SLOT1;
      const float* __restrict__ Whprev = Wh  + (size_t)i*SLOTW;
      float acc[8] = {0,0,0,0,0,0,0,0};
      int k0 = wave*29, k1 = min(k0 + 29, 463);
      { int ka = k0, kb = min(k1, 400);
        if (kb > ka) gemv_seg(H1prev + ka*64, WL1S + ka*CB1, kb-ka, bg4, cg2, acc); }
      { int ka = max(k0,400), kb = min(k1, 460);
        if (kb > ka) gemv_seg(Whprev + (ka-400)*64, WL1S + ka*CB1, kb-ka, bg4, cg2, acc); }
      { int ka = max(k0,460), kb = k1;
        if (kb > ka) gemv_seg(XST + i*192 + (ka-460)*64, WL1S + ka*CB1, kb-ka, bg4, cg2, acc); }
      *(float4*)&PARTS[(wave*CB1 + cg2  )*64 + bg4] = make_float4(acc[0],acc[1],acc[2],acc[3]);
      *(float4*)&PARTS[(wave*CB1 + cg2+1)*64 + bg4] = make_float4(acc[4],acc[5],acc[6],acc[7]);
      __syncthreads();
      if (tid < 512){
        int c = tid>>6, b = tid&63; float s = 0.f;
        #pragma unroll
        for (int w16=0; w16<NWAVE; ++w16) s += PARTS[(w16*CB1 + c)*64 + b];
        GREDS[c*64 + b] = s;
      }
      __syncthreads();
      if (tid < 128){
        int u = tid>>6, b = tid&63, j = 2*p + u;
        float gi = GREDS[(0+u)*64+b] + BS1S[0+u];
        float gf = GREDS[(2+u)*64+b] + BS1S[2+u];
        float gg = GREDS[(4+u)*64+b] + BS1S[4+u];
        float go = GREDS[(6+u)*64+b] + BS1S[6+u];
        float c_ = sigm(gf)*CS1S[u*64+b] + sigm(gi)*tanhf(gg);
        float h_ = sigm(go)*tanhf(c_);
        CS1S[u*64+b] = c_;
        st_agent(&H1t[(size_t)(i+1)*SLOT1 + j*64 + b], h_);   // publish h1(i)
        if (i == TT-1){ outp[H0F_OFF + b*HIDN + j] = h_; outp[C0F_OFF + b*HIDN + j] = c_; }
      }
      __syncthreads();                       // drain vmcnt: h1 publish complete
      if (tid == 0) st_agent_i(&cnts[CAW(p)], i+1);
    }

    // ---- window blocks: window for step i ----
    if (isWin && i < TT){
      const int b = p;
      if (tid < PBLK) spin_ge(&cnts[CAW(tid)], i+1);
      asm volatile("" ::: "memory");
      __syncthreads();
      const float* __restrict__ H1now = H1t + (size_t)(i+1)*SLOT1;
      for (int k = tid; k < HIDN; k += THR) HBUFS[k] = H1now[k*64 + b];
      __syncthreads();
      if (tid < 480){
        int j = tid >> 4, l = tid & 15;
        float s = 0.f;
        for (int k = l; k < HIDN; k += 16) s = fmaf(HBUFS[k], WWINS[j*HIDN + k], s);
        s += __shfl_down(s, 8, 16);
        s += __shfl_down(s, 4, 16);
        s += __shfl_down(s, 2, 16);
        s += __shfl_down(s, 1, 16);
        if (l == 0) PWS[j] = expf(s + bwin[j]);
      }
      __syncthreads();
      if (tid < KK) KAPS[tid] += PWS[20 + tid];
      __syncthreads();
      if (tid < UU){
        float u = (float)tid, s = 0.f;
        #pragma unroll
        for (int q = 0; q < KK; ++q){
          float d = KAPS[q] - u;
          s = fmaf(PWS[q], expf(-PWS[KK+q]*d*d), s);
        }
        s *= TMSKS[tid];
        PHIS[tid] = s;
        if (i == TT-1) outp[PHI_OFF + b*UU + tid] = s;
      }
      __syncthreads();
      if (tid < DD){
        float s = 0.f;
        for (int u = 0; u < UU; ++u) s = fmaf(PHIS[u], ONEHS[u*DD + tid], s);
        st_agent(&Wh[(size_t)(i+1)*SLOTW + tid*64 + b], s);   // publish w(i)
        if (i == TT-1) outp[WF_OFF + b*DD + tid] = s;
      }
      if (tid < KK && i == TT-1) outp[KAPPA_OFF + b*KK + tid] = KAPS[tid];
      __syncthreads();                       // drain w publish
      if (tid == 0) st_agent_i(&cnts[CWW(p)], i+1);
    }

    // ---- GEMV2 blocks: h2 step t2 = i-1 ----
    if (isG2 && i >= 1){
      const int t2 = i - 1;
      const float* __restrict__ H1cur = H1t + (size_t)i*SLOT1;
      const float* __restrict__ H2pp  = H2t + (size_t)(i-1)*SLOT1;
      const float* __restrict__ Whcur = Wh  + (size_t)i*SLOTW;
      float acc[16];
      #pragma unroll
      for (int z=0; z<16; ++z) acc[z] = 0.f;
      int k0 = wave*54, k1 = min(k0 + 54, 863);
      { int ka = k0, kb = min(k1, 400);
        if (kb > ka) gemv_seg2(H1cur + ka*64, WL2S + ka*CB2, kb-ka, bg8, c2g2, acc); }
      { int ka = max(k0,400), kb = min(k1, 800);
        if (kb > ka) gemv_seg2(H2pp + (ka-400)*64, WL2S + ka*CB2, kb-ka, bg8, c2g2, acc); }
      { int ka = max(k0,800), kb = min(k1, 860);
        if (kb > ka) gemv_seg2(Whcur + (ka-800)*64, WL2S + ka*CB2, kb-ka, bg8, c2g2, acc); }
      { int ka = max(k0,860), kb = k1;
        if (kb > ka) gemv_seg2(XST + t2*192 + (ka-860)*64, WL2S + ka*CB2, kb-ka, bg8, c2g2, acc); }
      __syncthreads();                       // PARTS free (GEMV1 reduce done)
      *(float4*)&PARTS[(wave*CB2 + c2g2  )*64 + bg8    ] = make_float4(acc[0],acc[1],acc[2],acc[3]);
      *(float4*)&PARTS[(wave*CB2 + c2g2  )*64 + bg8 + 4] = make_float4(acc[4],acc[5],acc[6],acc[7]);
      *(float4*)&PARTS[(wave*CB2 + c2g2+1)*64 + bg8    ] = make_float4(acc[8],acc[9],acc[10],acc[11]);
      *(float4*)&PARTS[(wave*CB2 + c2g2+1)*64 + bg8 + 4] = make_float4(acc[12],acc[13],acc[14],acc[15]);
      __syncthreads();
      {
        int c = tid>>6, b = tid&63; float s = 0.f;
        #pragma unroll
        for (int w16=0; w16<NWAVE; ++w16) s += PARTS[(w16*CB2 + c)*64 + b];
        GREDS[c*64 + b] = s;
      }
      __syncthreads();
      if (tid < 256){
        int uu = tid>>6, b = tid&63, j = 4*(p-NWB) + uu;
        float gi = GREDS[( 0+uu)*64+b] + BS2S[ 0+uu];
        float gf = GREDS[( 4+uu)*64+b] + BS2S[ 4+uu];
        float gg = GREDS[( 8+uu)*64+b] + BS2S[ 8+uu];
        float go = GREDS[(12+uu)*64+b] + BS2S[12+uu];
        float c_ = sigm(gf)*CS2S[uu*64+b] + sigm(gi)*tanhf(gg);
        float h_ = sigm(go)*tanhf(c_);
        CS2S[uu*64+b] = c_;
        st_agent(&H2t[(size_t)i*SLOT1 + j*64 + b], h_);       // publish h2(i-1)
        if (i == TT){ outp[H1F_OFF + b*HIDN + j] = h_; outp[C1F_OFF + b*HIDN + j] = c_; }
      }
      if (i < TT){
        __syncthreads();                     // drain h2 publish
        if (tid == 0) st_agent_i(&cnts[CHW(p-NWB)], i);
      }
    }
  }
}

// ---------- FC + heads: one block per timestep ----------
__global__ __launch_bounds__(128) void fc2_kernel(
    const float* __restrict__ H1t, const float* __restrict__ H2t,
    const float* __restrict__ WfcT, const float* __restrict__ bfc,
    float* __restrict__ outp)
{
  const int t   = blockIdx.x;
  const int tid = threadIdx.x;
  __shared__ float Xs[8][64];
  __shared__ float OUT[FCOUT][65];
  float acc[64];
  #pragma unroll
  for (int b=0;b<64;++b) acc[b]=0.f;
  const float* __restrict__ base1 = H1t + (size_t)(t+1)*SLOT1;
  const float* __restrict__ base2 = H2t + (size_t)(t+1)*SLOT1;

  for (int kb=0; kb<100; ++kb){
    __syncthreads();
    #pragma unroll
    for (int e=0;e<4;++e){
      int idx = e*128 + tid;
      int row = idx>>6, b = idx&63;
      int k = kb*8 + row;
      Xs[row][b] = (k<400) ? base1[k*64+b] : base2[(k-400)*64+b];
    }
    __syncthreads();
    if (tid < FCOUT){
      #pragma unroll
      for (int kk=0;kk<8;++kk){
        float wv = WfcT[(kb*8+kk)*FCOUT + tid];
        #pragma unroll
        for (int b4=0;b4<16;++b4){
          float4 xv = *(const float4*)&Xs[kk][b4*4];
          acc[b4*4+0] = fmaf(wv, xv.x, acc[b4*4+0]);
          acc[b4*4+1] = fmaf(wv, xv.y, acc[b4*4+1]);
          acc[b4*4+2] = fmaf(wv, xv.z, acc[b4*4+2]);
          acc[b4*4+3] = fmaf(wv, xv.w, acc[b4*4+3]);
        }
      }
    }
  }
  if (tid < FCOUT){
    float bj = bfc[tid];
    #pragma unroll
    for (int b=0;b<64;++b) OUT[tid][b] = acc[b] + bj;
  }
  __syncthreads();
  if (tid < 64){
    const int b = tid;
    const size_t pos = (size_t)b*TT + t;
    for (int j=0;j<40;++j) outp[MU_OFF  + pos*40 + j] = OUT[j][b];
    for (int j=0;j<40;++j) outp[SIG_OFF + pos*40 + j] = OUT[40+j][b];
    float m = -1e30f;
    for (int q=0;q<20;++q) m = fmaxf(m, OUT[80+q][b]);
    float e[20], s=0.f;
    for (int q=0;q<20;++q){ e[q]=expf(OUT[80+q][b]-m); s+=e[q]; }
    float inv = 1.f/s;
    for (int q=0;q<20;++q) outp[PI_OFF  + pos*20 + q] = e[q]*inv;
    for (int q=0;q<20;++q) outp[RHO_OFF + pos*20 + q] = tanhf(OUT[100+q][b]);
    outp[EOS_OFF + pos] = 1.0f/(1.0f + expf(OUT[120][b]));
  }
}

extern "C" void kernel_launch(void* const* d_in, const int* in_sizes, int n_in,
                              void* d_out, int out_size, void* d_ws, size_t ws_size,
                              hipStream_t stream){
  (void)in_sizes; (void)n_in; (void)out_size; (void)ws_size;
  const float* strokes = (const float*)d_in[0];
  const float* onehots = (const float*)d_in[1];
  const float* tmask   = (const float*)d_in[2];
  const float* Wih1    = (const float*)d_in[3];
  const float* Whh1    = (const float*)d_in[4];
  const float* b1      = (const float*)d_in[5];
  const float* Wwin    = (const float*)d_in[6];
  const float* bwin    = (const float*)d_in[7];
  const float* Wih2    = (const float*)d_in[8];
  const float* Whh2    = (const float*)d_in[9];
  const float* b2      = (const float*)d_in[10];
  const float* Wfc     = (const float*)d_in[11];
  const float* bfc     = (const float*)d_in[12];

  float* ws    = (float*)d_ws;
  float* outp  = (float*)d_out;
  float* H1t   = ws + WS_H1T;
  float* H2t   = ws + WS_H2T;
  float* Wh    = ws + WS_WHT;
  float* XST   = ws + WS_XST;
  float* WALL1 = ws + WS_WALL1;
  float* WALL2 = ws + WS_WALL2;
  float* WfcT  = ws + WS_WFCT;
  int*   cnts  = (int*)(ws + WS_CNT);

  hipLaunchKernelGGL(prep_init, dim3((TT*3*64 + 255)/256), dim3(256), 0, stream,
                     onehots, strokes, H1t, H2t, Wh, XST, cnts);
  hipLaunchKernelGGL(prep_wall, dim3((2121600 + 255)/256), dim3(256), 0, stream,
                     Wih1, Whh1, Wih2, Whh2, WALL1, WALL2);
  hipLaunchKernelGGL(prep_wfc, dim3((FCIN*FCOUT + 255)/256), dim3(256), 0, stream,
                     Wfc, WfcT);

  hipLaunchKernelGGL(recurrent_kernel, dim3(PBLK), dim3(THR), 0, stream,
                     Wwin, bwin, b1, b2, tmask, onehots, WALL1, WALL2,
                     H1t, H2t, Wh, XST, cnts, outp);

  hipLaunchKernelGGL(fc2_kernel, dim3(TT), dim3(128), 0, stream,
                     H1t, H2t, WfcT, bfc, outp);
}

// Round 8
// 9625.674 us; speedup vs baseline: 2.1846x; 2.1846x over previous
//
#include <hip/hip_runtime.h>
#include <hip/hip_bf16.h>
#include <math.h>

#define HIDN 400
#define KK   10
#define UU   64
#define DD   60
#define TT   600
#define BB   64
#define FCIN 800
#define FCOUT 121

#define PBLK 200      // unit blocks (2 hidden units of both LSTMs each)
#define NWBK 16       // window blocks (4 batches each)
#define WBAT 4
#define TOTB (PBLK + NWBK)   // 216 blocks, 1/CU via 125KB LDS
#define THR  1024     // 16 waves
#define NWAVE 16
#define CB   8        // gate-cols per unit block per LSTM

#define SLOT1 25600   // 400*64
#define SLOTW 3840    // 60*64

// ---- d_out offsets (floats) ----
#define PI_OFF    0
#define MU_OFF    768000
#define SIG_OFF   2304000
#define RHO_OFF   3840000
#define EOS_OFF   4608000
#define WF_OFF    4646400
#define KAPPA_OFF 4650240
#define PHI_OFF   4650880
#define H0F_OFF   4654976
#define C0F_OFF   4680576
#define H1F_OFF   4706176
#define C1F_OFF   4731776

// ---- workspace offsets (floats) ----
#define WS_H1T   0                  // 601*25600
#define WS_H2T   15385600           // 601*25600
#define WS_WHT   30771200           // 601*3840
#define WS_XST   33079040           // 600*3*64
#define WS_WALL1 33194240           // 200*463*8
#define WS_WALL2 33935040           // 200*863*8
#define WS_WFCT  35315840           // 800*121
#define WS_CNT   35412640           // 6656 ints
// total ~= 35,419,296 floats = 141.7 MB (== round-6 footprint)

// ---- grouped barrier counters (8 arrivals/line, modulo-8 window, monotone) ----
#define CAI(i,g) ((((i)&7)*25+(g))*16)            // h1: 25 groups of 8 unit blocks
#define CWI(i,g) (3200 + (((i)&7)*2+(g))*16)      // w : 2 groups of 8 window blocks
#define CHI(i,g) (3456 + (((i)&7)*25+(g))*16)     // h2: 25 groups
#define CNT_INTS 6656
#define TGT(i)   ((((i)>>3)+1)*8)

// ---- LDS layout (floats), unit/window overlaid; 31264 fl = 125KB -> 1 blk/CU ----
#define S_WL1   0        // 3704  unit
#define S_WL2   3704     // 6904
#define S_PART  10608    // 8192
#define S_GRED  18800    // 512
#define S_CS1   19312    // 128
#define S_CS2   19440    // 128
#define S_BS1   19568    // 8
#define S_BS2   19576    // 8
#define S_WWT   0        // 13200 window (Wwin transposed, stride 33)
#define S_ONE   13200    // 15360 (4 batches' onehots)
#define S_H1S   28560    // 2000  (h1 tile [400][5])
#define S_TMS   30560    // 256
#define S_PW    30816    // 128   ([4][32])
#define S_KAP   30944    // 64    ([4][16])
#define S_PHI   31008    // 256   ([4][64])
#define SMEM_F  31264

__device__ __forceinline__ float sigm(float x){ return 1.0f/(1.0f + expf(-x)); }

__device__ __forceinline__ void st_agent(float* p, float v){
  __hip_atomic_store(p, v, __ATOMIC_RELAXED, __HIP_MEMORY_SCOPE_AGENT);
}
__device__ __forceinline__ int ld_agent_i(const int* p){
  return __hip_atomic_load(p, __ATOMIC_RELAXED, __HIP_MEMORY_SCOPE_AGENT);
}
__device__ __forceinline__ void arrive(int* p){
  __hip_atomic_fetch_add(p, 1, __ATOMIC_RELAXED, __HIP_MEMORY_SCOPE_AGENT);
}
__device__ __forceinline__ void spin_ge(const int* w, int tgt){
  if (ld_agent_i(w) >= tgt) return;
  do { __builtin_amdgcn_s_sleep(1); } while (ld_agent_i(w) < tgt);
}

// ---------- prep ----------
__global__ void prep_init(const float* __restrict__ onehots, const float* __restrict__ strokes,
                          float* __restrict__ H1t, float* __restrict__ H2t,
                          float* __restrict__ Wh,  float* __restrict__ XST,
                          int* __restrict__ cnts){
  int idx = blockIdx.x*blockDim.x + threadIdx.x;
  if (idx < SLOT1){ H1t[idx] = 0.f; H2t[idx] = 0.f; }
  if (idx < SLOTW){
    int d = idx >> 6, b = idx & 63;
    Wh[idx] = onehots[b*(UU*DD) + d];            // onehots[b, u=0, d]
  }
  if (idx < TT*3*64){
    int t = idx/192, rem = idx%192, comp = rem/64, b = rem%64;
    XST[idx] = strokes[(b*TT + t)*3 + comp];
  }
  if (idx < CNT_INTS) cnts[idx] = 0;
}

// ---------- weight reorder (round-6 layout: CB=8 for both LSTMs) ----------
// unit block p owns hidden units {2p,2p+1}; col c = 2*q + (j&1); gates q: 0=i,1=f,2=g,3=o
// WALL1 rows: [0,400)=h1, [400,460)=w, [460,463)=x
// WALL2 rows: [0,400)=h1, [400,800)=h2, [800,860)=w, [860,863)=x
__global__ void prep_wall(const float* __restrict__ Wih1, const float* __restrict__ Whh1,
                          const float* __restrict__ Wih2, const float* __restrict__ Whh2,
                          float* __restrict__ WALL1, float* __restrict__ WALL2){
  int idx = blockIdx.x*blockDim.x + threadIdx.x;
  if (idx < 640000){                       // W_hh1 (1600,400)
    int g = idx/400, k = idx%400;
    int q = g/400, j = g%400, p = j>>1, c = 2*q + (j&1);
    WALL1[(p*463 + k)*CB + c] = Whh1[idx];
  } else if (idx < 740800){                // W_ih1 (1600,63)
    int s = idx - 640000;
    int g = s/63, col = s%63;
    int q = g/400, j = g%400, p = j>>1, c = 2*q + (j&1);
    int r = (col < 3) ? (460 + col) : (400 + col - 3);
    WALL1[(p*463 + r)*CB + c] = Wih1[s];
  } else if (idx < 1380800){               // W_hh2 (1600,400)
    int s = idx - 740800;
    int g = s/400, k = s%400;
    int q = g/400, j = g%400, p = j>>1, c = 2*q + (j&1);
    WALL2[(p*863 + 400 + k)*CB + c] = Whh2[s];
  } else if (idx < 2121600){               // W_ih2 (1600,463)
    int s = idx - 1380800;
    int g = s/463, col = s%463;
    int q = g/400, j = g%400, p = j>>1, c = 2*q + (j&1);
    int r = (col<3) ? (860+col) : (col<63 ? (800+col-3) : (col-63));
    WALL2[(p*863 + r)*CB + c] = Wih2[s];
  }
}

__global__ void prep_wfc(const float* __restrict__ Wfc, float* __restrict__ WfcT){
  int idx = blockIdx.x*blockDim.x + threadIdx.x;
  if (idx >= FCIN*FCOUT) return;
  int k = idx / FCOUT, j = idx - k*FCOUT;
  WfcT[idx] = Wfc[j*FCIN + k];
}

// ---------- GEMV segment (round-6, CB=8) ----------
__device__ __forceinline__ void gemv_seg(const float* __restrict__ x,
                                         const float* __restrict__ w,
                                         int n, int bg4, int cg2, float acc[8]){
  #pragma unroll 4
  for (int k=0;k<n;++k){
    const float4 xv = *(const float4*)(x + k*64 + bg4);
    const float2 wv = *(const float2*)(w + k*CB + cg2);
    acc[0] = fmaf(wv.x, xv.x, acc[0]);
    acc[1] = fmaf(wv.x, xv.y, acc[1]);
    acc[2] = fmaf(wv.x, xv.z, acc[2]);
    acc[3] = fmaf(wv.x, xv.w, acc[3]);
    acc[4] = fmaf(wv.y, xv.x, acc[4]);
    acc[5] = fmaf(wv.y, xv.y, acc[5]);
    acc[6] = fmaf(wv.y, xv.z, acc[6]);
    acc[7] = fmaf(wv.y, xv.w, acc[7]);
  }
}

// ---------- persistent recurrent kernel ----------
__global__ __launch_bounds__(THR) void recurrent_kernel(
    const float* __restrict__ Wwin, const float* __restrict__ bwin,
    const float* __restrict__ b1g,  const float* __restrict__ b2g,
    const float* __restrict__ tmask,const float* __restrict__ onehots,
    const float* __restrict__ WALL1,const float* __restrict__ WALL2,
    float* __restrict__ H1t,        float* __restrict__ H2t,
    float* __restrict__ Wh,         const float* __restrict__ XST,
    int* __restrict__ cnts,         float* __restrict__ outp)
{
  const int p   = blockIdx.x;
  const int tid = threadIdx.x;
  __shared__ float SM[SMEM_F];

  if (p < PBLK){
    // ================= UNIT BLOCK =================
    const int wave = tid >> 6, lane = tid & 63;
    const int bg4  = (lane & 15) * 4;
    const int cg2  = (lane >> 4) * 2;
    float* WL1 = SM + S_WL1;  float* WL2 = SM + S_WL2;
    float* PART= SM + S_PART; float* GRED= SM + S_GRED;
    float* CS1 = SM + S_CS1;  float* CS2 = SM + S_CS2;
    float* BS1 = SM + S_BS1;  float* BS2 = SM + S_BS2;

    for (int idx = tid; idx < 463*CB; idx += THR) WL1[idx] = WALL1[p*463*CB + idx];
    for (int idx = tid; idx < 863*CB; idx += THR) WL2[idx] = WALL2[p*863*CB + idx];
    if (tid < CB){ int q = tid>>1, u = tid&1; int j = 2*p+u;
      BS1[tid] = b1g[q*HIDN + j]; BS2[tid] = b2g[q*HIDN + j]; }
    if (tid < 128){ CS1[tid] = 0.f; CS2[tid] = 0.f; }
    __syncthreads();

    for (int i = 0; i <= TT; ++i){
      // merged top wait: CA(i-1), CW(i-1), CH(i-2)
      if (i >= 1){
        if (tid < 25)                  spin_ge(&cnts[CAI(i-1, tid)],   TGT(i-1));
        else if (tid >= 32 && tid < 34) spin_ge(&cnts[CWI(i-1, tid-32)], TGT(i-1));
        else if (tid >= 64 && tid < 89){ if (i >= 2) spin_ge(&cnts[CHI(i-2, tid-64)], TGT(i-2)); }
        asm volatile("" ::: "memory");
        __syncthreads();
      }

      if (i < TT){
        // GEMV1 step i: h1(i-1)[0,400), w(i-1)[400,460), x(i)[460,463)
        const float* __restrict__ H1prev = H1t + (size_t)i*SLOT1;
        const float* __restrict__ Whprev = Wh  + (size_t)i*SLOTW;
        float acc[8] = {0,0,0,0,0,0,0,0};
        int k0 = wave*29, k1 = min(k0 + 29, 463);
        { int ka = k0, kb = min(k1, 400);
          if (kb > ka) gemv_seg(H1prev + ka*64, WL1 + ka*CB, kb-ka, bg4, cg2, acc); }
        { int ka = max(k0,400), kb = min(k1, 460);
          if (kb > ka) gemv_seg(Whprev + (ka-400)*64, WL1 + ka*CB, kb-ka, bg4, cg2, acc); }
        { int ka = max(k0,460), kb = k1;
          if (kb > ka) gemv_seg(XST + i*192 + (ka-460)*64, WL1 + ka*CB, kb-ka, bg4, cg2, acc); }
        *(float4*)&PART[(wave*CB + cg2  )*64 + bg4] = make_float4(acc[0],acc[1],acc[2],acc[3]);
        *(float4*)&PART[(wave*CB + cg2+1)*64 + bg4] = make_float4(acc[4],acc[5],acc[6],acc[7]);
        __syncthreads();
        if (tid < 512){
          int c = tid>>6, b = tid&63; float s = 0.f;
          #pragma unroll
          for (int w16=0; w16<NWAVE; ++w16) s += PART[(w16*CB + c)*64 + b];
          GRED[c*64 + b] = s;
        }
        __syncthreads();
        if (tid < 128){
          int u = tid>>6, b = tid&63, j = 2*p + u;
          float gi = GRED[(0+u)*64+b] + BS1[0+u];
          float gf = GRED[(2+u)*64+b] + BS1[2+u];
          float gg = GRED[(4+u)*64+b] + BS1[4+u];
          float go = GRED[(6+u)*64+b] + BS1[6+u];
          float c_ = sigm(gf)*CS1[u*64+b] + sigm(gi)*tanhf(gg);
          float h_ = sigm(go)*tanhf(c_);
          CS1[u*64+b] = c_;
          st_agent(&H1t[(size_t)(i+1)*SLOT1 + j*64 + b], h_);   // publish h1(i)
          if (i == TT-1){ outp[H0F_OFF + b*HIDN + j] = h_; outp[C0F_OFF + b*HIDN + j] = c_; }
        }
        __syncthreads();                     // drain vmcnt (publish complete)
        if (tid == 0) arrive(&cnts[CAI(i, p>>3)]);
      }

      if (i >= 1){
        // GEMV2 step t2=i-1: h1(i-1)[0,400), h2(i-2)[400,800), w(i-1)[800,860), x[860,863)
        const int t2 = i - 1;
        const float* __restrict__ H1cur = H1t + (size_t)i*SLOT1;
        const float* __restrict__ H2pp  = H2t + (size_t)(i-1)*SLOT1;
        const float* __restrict__ Whcur = Wh  + (size_t)i*SLOTW;
        float acc[8] = {0,0,0,0,0,0,0,0};
        int k0 = wave*54, k1 = min(k0 + 54, 863);
        { int ka = k0, kb = min(k1, 400);
          if (kb > ka) gemv_seg(H1cur + ka*64, WL2 + ka*CB, kb-ka, bg4, cg2, acc); }
        { int ka = max(k0,400), kb = min(k1, 800);
          if (kb > ka) gemv_seg(H2pp + (ka-400)*64, WL2 + ka*CB, kb-ka, bg4, cg2, acc); }
        { int ka = max(k0,800), kb = min(k1, 860);
          if (kb > ka) gemv_seg(Whcur + (ka-800)*64, WL2 + ka*CB, kb-ka, bg4, cg2, acc); }
        { int ka = max(k0,860), kb = k1;
          if (kb > ka) gemv_seg(XST + t2*192 + (ka-860)*64, WL2 + ka*CB, kb-ka, bg4, cg2, acc); }
        __syncthreads();                     // PART free
        *(float4*)&PART[(wave*CB + cg2  )*64 + bg4] = make_float4(acc[0],acc[1],acc[2],acc[3]);
        *(float4*)&PART[(wave*CB + cg2+1)*64 + bg4] = make_float4(acc[4],acc[5],acc[6],acc[7]);
        __syncthreads();
        if (tid < 512){
          int c = tid>>6, b = tid&63; float s = 0.f;
          #pragma unroll
          for (int w16=0; w16<NWAVE; ++w16) s += PART[(w16*CB + c)*64 + b];
          GRED[c*64 + b] = s;
        }
        __syncthreads();
        if (tid < 128){
          int u = tid>>6, b = tid&63, j = 2*p + u;
          float gi = GRED[(0+u)*64+b] + BS2[0+u];
          float gf = GRED[(2+u)*64+b] + BS2[2+u];
          float gg = GRED[(4+u)*64+b] + BS2[4+u];
          float go = GRED[(6+u)*64+b] + BS2[6+u];
          float c_ = sigm(gf)*CS2[u*64+b] + sigm(gi)*tanhf(gg);
          float h_ = sigm(go)*tanhf(c_);
          CS2[u*64+b] = c_;
          st_agent(&H2t[(size_t)i*SLOT1 + j*64 + b], h_);       // publish h2(i-1)
          if (i == TT){ outp[H1F_OFF + b*HIDN + j] = h_; outp[C1F_OFF + b*HIDN + j] = c_; }
        }
        if (i < TT){
          __syncthreads();                   // drain h2 publish
          if (tid == 0) arrive(&cnts[CHI(i-1, p>>3)]);
        }
      }
    }
  } else {
    // ================= WINDOW BLOCK (4 batches) =================
    const int wb = p - PBLK;
    const int b0 = wb * WBAT;
    float* WWT = SM + S_WWT;  float* ONE = SM + S_ONE;
    float* H1S = SM + S_H1S;  float* TMS = SM + S_TMS;
    float* PW  = SM + S_PW;   float* KAP = SM + S_KAP;
    float* PHI = SM + S_PHI;

    for (int idx = tid; idx < 30*400; idx += THR){
      int j = idx/400, k = idx - j*400;
      WWT[k*33 + j] = Wwin[idx];
    }
    for (int idx = tid; idx < WBAT*UU*DD; idx += THR) ONE[idx] = onehots[b0*(UU*DD) + idx];
    if (tid < WBAT*UU) TMS[tid] = tmask[b0*UU + tid];
    if (tid < WBAT*16) KAP[tid] = 0.f;
    __syncthreads();

    for (int i = 0; i < TT; ++i){
      if (tid < 25) spin_ge(&cnts[CAI(i, tid)], TGT(i));
      asm volatile("" ::: "memory");
      __syncthreads();
      // stage h1(i) tile [400][WBAT] (pad 5)
      const float* __restrict__ H1now = H1t + (size_t)(i+1)*SLOT1;
      for (int idx = tid; idx < 400*WBAT; idx += THR){
        int r = idx >> 2, c = idx & 3;
        H1S[r*5 + c] = H1now[r*64 + b0 + c];
      }
      __syncthreads();
      // dots: 480 threads = (b,j) pairs x 4-way k split
      if (tid < 480){
        int ks = tid & 3, pair = tid >> 2;
        int b = pair / 30, j = pair - b*30;
        float s = 0.f;
        #pragma unroll 4
        for (int kk = 0; kk < 100; ++kk){
          int k = ks*100 + kk;
          s = fmaf(H1S[k*5 + b], WWT[k*33 + j], s);
        }
        s += __shfl_down(s, 2, 4);
        s += __shfl_down(s, 1, 4);
        if (ks == 0) PW[b*32 + j] = expf(s + bwin[j]);
      }
      __syncthreads();
      if (tid < WBAT*KK){
        int b = tid/KK, k = tid - b*KK;
        KAP[b*16 + k] += PW[b*32 + 20 + k];
      }
      __syncthreads();
      // phi: 256 threads (b,u)
      if (tid < WBAT*UU){
        int b = tid >> 6, u = tid & 63;
        float uf = (float)u, s = 0.f;
        #pragma unroll
        for (int q = 0; q < KK; ++q){
          float d = KAP[b*16 + q] - uf;
          s = fmaf(PW[b*32 + q], expf(-PW[b*32 + 10 + q]*d*d), s);
        }
        s *= TMS[b*64 + u];
        PHI[b*64 + u] = s;
        if (i == TT-1) outp[PHI_OFF + (b0+b)*UU + u] = s;
      }
      __syncthreads();
      // w: 240 threads (b,d)
      if (tid < WBAT*DD){
        int b = tid/DD, d = tid - b*DD;
        float s = 0.f;
        #pragma unroll 8
        for (int u = 0; u < UU; ++u) s = fmaf(PHI[b*64 + u], ONE[b*(UU*DD) + u*DD + d], s);
        st_agent(&Wh[(size_t)(i+1)*SLOTW + d*64 + b0 + b], s);  // publish w(i)
        if (i == TT-1) outp[WF_OFF + (b0+b)*DD + d] = s;
      }
      if (i == TT-1 && tid < WBAT*KK){
        int b = tid/KK, k = tid - b*KK;
        outp[KAPPA_OFF + (b0+b)*KK + k] = KAP[b*16 + k];
      }
      __syncthreads();                       // drain w publish
      if (tid == 0) arrive(&cnts[CWI(i, wb>>3)]);
    }
  }
}

// ---------- FC + heads: one block per timestep ----------
__global__ __launch_bounds__(128) void fc2_kernel(
    const float* __restrict__ H1t, const float* __restrict__ H2t,
    const float* __restrict__ WfcT, const float* __restrict__ bfc,
    float* __restrict__ outp)
{
  const int t   = blockIdx.x;
  const int tid = threadIdx.x;
  __shared__ float Xs[8][64];
  __shared__ float OUT[FCOUT][65];
  float acc[64];
  #pragma unroll
  for (int b=0;b<64;++b) acc[b]=0.f;
  const float* __restrict__ base1 = H1t + (size_t)(t+1)*SLOT1;
  const float* __restrict__ base2 = H2t + (size_t)(t+1)*SLOT1;

  for (int kb=0; kb<100; ++kb){
    __syncthreads();
    #pragma unroll
    for (int e=0;e<4;++e){
      int idx = e*128 + tid;
      int row = idx>>6, b = idx&63;
      int k = kb*8 + row;
      Xs[row][b] = (k<400) ? base1[k*64+b] : base2[(k-400)*64+b];
    }
    __syncthreads();
    if (tid < FCOUT){
      #pragma unroll
      for (int kk=0;kk<8;++kk){
        float wv = WfcT[(kb*8+kk)*FCOUT + tid];
        #pragma unroll
        for (int b4=0;b4<16;++b4){
          float4 xv = *(const float4*)&Xs[kk][b4*4];
          acc[b4*4+0] = fmaf(wv, xv.x, acc[b4*4+0]);
          acc[b4*4+1] = fmaf(wv, xv.y, acc[b4*4+1]);
          acc[b4*4+2] = fmaf(wv, xv.z, acc[b4*4+2]);
          acc[b4*4+3] = fmaf(wv, xv.w, acc[b4*4+3]);
        }
      }
    }
  }
  if (tid < FCOUT){
    float bj = bfc[tid];
    #pragma unroll
    for (int b=0;b<64;++b) OUT[tid][b] = acc[b] + bj;
  }
  __syncthreads();
  if (tid < 64){
    const int b = tid;
    const size_t pos = (size_t)b*TT + t;
    for (int j=0;j<40;++j) outp[MU_OFF  + pos*40 + j] = OUT[j][b];
    for (int j=0;j<40;++j) outp[SIG_OFF + pos*40 + j] = OUT[40+j][b];
    float m = -1e30f;
    for (int q=0;q<20;++q) m = fmaxf(m, OUT[80+q][b]);
    float e[20], s=0.f;
    for (int q=0;q<20;++q){ e[q]=expf(OUT[80+q][b]-m); s+=e[q]; }
    float inv = 1.f/s;
    for (int q=0;q<20;++q) outp[PI_OFF  + pos*20 + q] = e[q]*inv;
    for (int q=0;q<20;++q) outp[RHO_OFF + pos*20 + q] = tanhf(OUT[100+q][b]);
    outp[EOS_OFF + pos] = 1.0f/(1.0f + expf(OUT[120][b]));
  }
}

extern "C" void kernel_launch(void* const* d_in, const int* in_sizes, int n_in,
                              void* d_out, int out_size, void* d_ws, size_t ws_size,
                              hipStream_t stream){
  (void)in_sizes; (void)n_in; (void)out_size; (void)ws_size;
  const float* strokes = (const float*)d_in[0];
  const float* onehots = (const float*)d_in[1];
  const float* tmask   = (const float*)d_in[2];
  const float* Wih1    = (const float*)d_in[3];
  const float* Whh1    = (const float*)d_in[4];
  const float* b1      = (const float*)d_in[5];
  const float* Wwin    = (const float*)d_in[6];
  const float* bwin    = (const float*)d_in[7];
  const float* Wih2    = (const float*)d_in[8];
  const float* Whh2    = (const float*)d_in[9];
  const float* b2      = (const float*)d_in[10];
  const float* Wfc     = (const float*)d_in[11];
  const float* bfc     = (const float*)d_in[12];

  float* ws    = (float*)d_ws;
  float* outp  = (float*)d_out;
  float* H1t   = ws + WS_H1T;
  float* H2t   = ws + WS_H2T;
  float* Wh    = ws + WS_WHT;
  float* XST   = ws + WS_XST;
  float* WALL1 = ws + WS_WALL1;
  float* WALL2 = ws + WS_WALL2;
  float* WfcT  = ws + WS_WFCT;
  int*   cnts  = (int*)(ws + WS_CNT);

  hipLaunchKernelGGL(prep_init, dim3((TT*3*64 + 255)/256), dim3(256), 0, stream,
                     onehots, strokes, H1t, H2t, Wh, XST, cnts);
  hipLaunchKernelGGL(prep_wall, dim3((2121600 + 255)/256), dim3(256), 0, stream,
                     Wih1, Whh1, Wih2, Whh2, WALL1, WALL2);
  hipLaunchKernelGGL(prep_wfc, dim3((FCIN*FCOUT + 255)/256), dim3(256), 0, stream,
                     Wfc, WfcT);

  hipLaunchKernelGGL(recurrent_kernel, dim3(TOTB), dim3(THR), 0, stream,
                     Wwin, bwin, b1, b2, tmask, onehots, WALL1, WALL2,
                     H1t, H2t, Wh, XST, cnts, outp);

  hipLaunchKernelGGL(fc2_kernel, dim3(TT), dim3(128), 0, stream,
                     H1t, H2t, WfcT, bfc, outp);
}

// Round 9
// 8938.177 us; speedup vs baseline: 2.3527x; 1.0769x over previous
//
#include <hip/hip_runtime.h>
#include <hip/hip_bf16.h>
#include <math.h>

#define HIDN 400
#define KK   10
#define UU   64
#define DD   60
#define TT   600
#define BB   64
#define FCIN 800
#define FCOUT 121

#define PBLK 200      // unit blocks (2 hidden units of both LSTMs each)
#define NWBK 32       // window blocks (2 batches each)
#define WBAT 2
#define TOTB (PBLK + NWBK)   // 232 blocks, 1/CU (LDS ~90KB)
#define THR  1024     // 16 waves
#define NWAVE 16
#define CB   8        // gate-cols per unit block per LSTM

#define SLOT1 25600   // 400*64
#define SLOTW 3840    // 60*64
#define SLOTT 25600   // 64*400 transposed slot

// ---- d_out offsets (floats) ----
#define PI_OFF    0
#define MU_OFF    768000
#define SIG_OFF   2304000
#define RHO_OFF   3840000
#define EOS_OFF   4608000
#define WF_OFF    4646400
#define KAPPA_OFF 4650240
#define PHI_OFF   4650880
#define H0F_OFF   4654976
#define C0F_OFF   4680576
#define H1F_OFF   4706176
#define C1F_OFF   4731776

// ---- workspace offsets (floats) ----
#define WS_H1T   0                  // 601*25600
#define WS_H2T   15385600           // 601*25600
#define WS_WHT   30771200           // 601*3840
#define WS_XST   33079040           // 600*3*64
#define WS_WALL1 33194240           // 200*463*8
#define WS_WALL2 33935040           // 200*863*8
#define WS_WFCT  35315840           // 800*121
#define WS_CNT   35412640           // 6912 ints
#define WS_H1TT  35419552           // 2*25600 transposed h1 ring
// total = 35,470,752 floats ~= 141.9 MB

// ---- grouped barrier counters (8 arrivals/line, modulo-8 window, monotone) ----
#define CAI(i,g) ((((i)&7)*25+(g))*16)            // h1: 25 groups of 8 unit blocks
#define CWI(i,g) (3200 + (((i)&7)*4+(g))*16)      // w : 4 groups of 8 window blocks
#define CHI(i,g) (3712 + (((i)&7)*25+(g))*16)     // h2: 25 groups
#define CNT_INTS 6912
#define TGT(i)   ((((i)>>3)+1)*8)

// ---- LDS layout (floats), unit/window overlaid ----
#define S_WL1   0        // 3704  unit
#define S_WL2   3704     // 6904
#define S_PART  10608    // 8192
#define S_GRED  18800    // 512
#define S_CS1   19312    // 128
#define S_CS2   19440    // 128
#define S_BS1   19568    // 8
#define S_BS2   19576    // 8   -> unit end 19584
#define S_WWT   0        // 13200 window (Wwin transposed, stride 33)
#define S_ONE   13200    // 7680  (2 batches' onehots)
#define S_H1S   20880    // 1200  (h1 tile [400][3])
#define S_TMS   22080    // 128
#define S_PW    22208    // 64    ([2][32])
#define S_KAP   22272    // 32    ([2][16])
#define S_PHI   22304    // 128   ([2][64])
#define SMEM_F  22432    // 89.7 KB -> 1 block/CU

__device__ __forceinline__ float sigm(float x){ return 1.0f/(1.0f + expf(-x)); }

__device__ __forceinline__ void st_agent(float* p, float v){
  __hip_atomic_store(p, v, __ATOMIC_RELAXED, __HIP_MEMORY_SCOPE_AGENT);
}
__device__ __forceinline__ int ld_agent_i(const int* p){
  return __hip_atomic_load(p, __ATOMIC_RELAXED, __HIP_MEMORY_SCOPE_AGENT);
}
__device__ __forceinline__ void arrive(int* p){
  __hip_atomic_fetch_add(p, 1, __ATOMIC_RELAXED, __HIP_MEMORY_SCOPE_AGENT);
}
__device__ __forceinline__ void spin_ge(const int* w, int tgt){
  if (ld_agent_i(w) >= tgt) return;
  do { __builtin_amdgcn_s_sleep(1); } while (ld_agent_i(w) < tgt);
}

// ---------- prep ----------
__global__ void prep_init(const float* __restrict__ onehots, const float* __restrict__ strokes,
                          float* __restrict__ H1t, float* __restrict__ H2t,
                          float* __restrict__ Wh,  float* __restrict__ XST,
                          int* __restrict__ cnts){
  int idx = blockIdx.x*blockDim.x + threadIdx.x;
  if (idx < SLOT1){ H1t[idx] = 0.f; H2t[idx] = 0.f; }
  if (idx < SLOTW){
    int d = idx >> 6, b = idx & 63;
    Wh[idx] = onehots[b*(UU*DD) + d];            // onehots[b, u=0, d]
  }
  if (idx < TT*3*64){
    int t = idx/192, rem = idx%192, comp = rem/64, b = rem%64;
    XST[idx] = strokes[(b*TT + t)*3 + comp];
  }
  if (idx < CNT_INTS) cnts[idx] = 0;
}

// ---------- weight reorder (CB=8 both LSTMs) ----------
// unit block p owns hidden units {2p,2p+1}; col c = 2*q + (j&1); gates q: 0=i,1=f,2=g,3=o
// WALL1 rows: [0,400)=h1, [400,460)=w, [460,463)=x
// WALL2 rows: [0,400)=h1, [400,800)=h2, [800,860)=w, [860,863)=x
__global__ void prep_wall(const float* __restrict__ Wih1, const float* __restrict__ Whh1,
                          const float* __restrict__ Wih2, const float* __restrict__ Whh2,
                          float* __restrict__ WALL1, float* __restrict__ WALL2){
  int idx = blockIdx.x*blockDim.x + threadIdx.x;
  if (idx < 640000){                       // W_hh1 (1600,400)
    int g = idx/400, k = idx%400;
    int q = g/400, j = g%400, p = j>>1, c = 2*q + (j&1);
    WALL1[(p*463 + k)*CB + c] = Whh1[idx];
  } else if (idx < 740800){                // W_ih1 (1600,63)
    int s = idx - 640000;
    int g = s/63, col = s%63;
    int q = g/400, j = g%400, p = j>>1, c = 2*q + (j&1);
    int r = (col < 3) ? (460 + col) : (400 + col - 3);
    WALL1[(p*463 + r)*CB + c] = Wih1[s];
  } else if (idx < 1380800){               // W_hh2 (1600,400)
    int s = idx - 740800;
    int g = s/400, k = s%400;
    int q = g/400, j = g%400, p = j>>1, c = 2*q + (j&1);
    WALL2[(p*863 + 400 + k)*CB + c] = Whh2[s];
  } else if (idx < 2121600){               // W_ih2 (1600,463)
    int s = idx - 1380800;
    int g = s/463, col = s%463;
    int q = g/400, j = g%400, p = j>>1, c = 2*q + (j&1);
    int r = (col<3) ? (860+col) : (col<63 ? (800+col-3) : (col-63));
    WALL2[(p*863 + r)*CB + c] = Wih2[s];
  }
}

__global__ void prep_wfc(const float* __restrict__ Wfc, float* __restrict__ WfcT){
  int idx = blockIdx.x*blockDim.x + threadIdx.x;
  if (idx >= FCIN*FCOUT) return;
  int k = idx / FCOUT, j = idx - k*FCOUT;
  WfcT[idx] = Wfc[j*FCIN + k];
}

// ---------- GEMV segment ----------
__device__ __forceinline__ void gemv_seg(const float* __restrict__ x,
                                         const float* __restrict__ w,
                                         int n, int bg4, int cg2, float acc[8]){
  #pragma unroll 4
  for (int k=0;k<n;++k){
    const float4 xv = *(const float4*)(x + k*64 + bg4);
    const float2 wv = *(const float2*)(w + k*CB + cg2);
    acc[0] = fmaf(wv.x, xv.x, acc[0]);
    acc[1] = fmaf(wv.x, xv.y, acc[1]);
    acc[2] = fmaf(wv.x, xv.z, acc[2]);
    acc[3] = fmaf(wv.x, xv.w, acc[3]);
    acc[4] = fmaf(wv.y, xv.x, acc[4]);
    acc[5] = fmaf(wv.y, xv.y, acc[5]);
    acc[6] = fmaf(wv.y, xv.z, acc[6]);
    acc[7] = fmaf(wv.y, xv.w, acc[7]);
  }
}

// ---------- persistent recurrent kernel ----------
__global__ __launch_bounds__(THR) void recurrent_kernel(
    const float* __restrict__ Wwin, const float* __restrict__ bwin,
    const float* __restrict__ b1g,  const float* __restrict__ b2g,
    const float* __restrict__ tmask,const float* __restrict__ onehots,
    const float* __restrict__ WALL1,const float* __restrict__ WALL2,
    float* __restrict__ H1t,        float* __restrict__ H2t,
    float* __restrict__ Wh,         const float* __restrict__ XST,
    float* __restrict__ H1TT,
    int* __restrict__ cnts,         float* __restrict__ outp)
{
  const int p   = blockIdx.x;
  const int tid = threadIdx.x;
  __shared__ float SM[SMEM_F];

  if (p < PBLK){
    // ================= UNIT BLOCK =================
    const int wave = tid >> 6, lane = tid & 63;
    const int bg4  = (lane & 15) * 4;
    const int cg2  = (lane >> 4) * 2;
    float* WL1 = SM + S_WL1;  float* WL2 = SM + S_WL2;
    float* PART= SM + S_PART; float* GRED= SM + S_GRED;
    float* CS1 = SM + S_CS1;  float* CS2 = SM + S_CS2;
    float* BS1 = SM + S_BS1;  float* BS2 = SM + S_BS2;

    for (int idx = tid; idx < 463*CB; idx += THR) WL1[idx] = WALL1[p*463*CB + idx];
    for (int idx = tid; idx < 863*CB; idx += THR) WL2[idx] = WALL2[p*863*CB + idx];
    if (tid < CB){ int q = tid>>1, u = tid&1; int j = 2*p+u;
      BS1[tid] = b1g[q*HIDN + j]; BS2[tid] = b2g[q*HIDN + j]; }
    if (tid < 128){ CS1[tid] = 0.f; CS2[tid] = 0.f; }
    __syncthreads();

    for (int i = 0; i <= TT; ++i){
      // ---- wait CA(i-1): h1(i-1) ready ----
      if (i >= 1){
        if (tid < 25) spin_ge(&cnts[CAI(i-1, tid)], TGT(i-1));
        asm volatile("" ::: "memory");
        __syncthreads();
      }

      float acc1[8] = {0,0,0,0,0,0,0,0};
      float acc2[8] = {0,0,0,0,0,0,0,0};

      // ---- GEMV1-A (step i): h1 rows [0,400) + x rows [460,463) ----
      if (i < TT){
        const float* __restrict__ H1prev = H1t + (size_t)i*SLOT1;
        int k0 = wave*26, k1 = min(k0 + 26, 403);
        { int ka = k0, kb = min(k1, 400);
          if (kb > ka) gemv_seg(H1prev + ka*64, WL1 + ka*CB, kb-ka, bg4, cg2, acc1); }
        { int ka = max(k0,400), kb = k1;
          if (kb > ka) gemv_seg(XST + i*192 + (ka-400)*64, WL1 + (460+ka-400)*CB, kb-ka, bg4, cg2, acc1); }
      }

      // ---- wait CH(i-2): h2(i-2) ready (usually free) ----
      if (i >= 2){
        if (tid < 25) spin_ge(&cnts[CHI(i-2, tid)], TGT(i-2));
        asm volatile("" ::: "memory");
        __syncthreads();
      }

      // ---- GEMV2-A (step i-1): h1 [0,400), h2 [400,800), x [860,863) ----
      if (i >= 1){
        const int t2 = i - 1;
        const float* __restrict__ H1cur = H1t + (size_t)i*SLOT1;
        const float* __restrict__ H2pp  = H2t + (size_t)(i-1)*SLOT1;
        int k0 = wave*51, k1 = min(k0 + 51, 803);
        { int ka = k0, kb = min(k1, 400);
          if (kb > ka) gemv_seg(H1cur + ka*64, WL2 + ka*CB, kb-ka, bg4, cg2, acc2); }
        { int ka = max(k0,400), kb = min(k1, 800);
          if (kb > ka) gemv_seg(H2pp + (ka-400)*64, WL2 + ka*CB, kb-ka, bg4, cg2, acc2); }
        { int ka = max(k0,800), kb = k1;
          if (kb > ka) gemv_seg(XST + t2*192 + (ka-800)*64, WL2 + (860+ka-800)*CB, kb-ka, bg4, cg2, acc2); }
      }

      // ---- wait CW(i-1): w(i-1) ready (window overlapped with A parts) ----
      if (i >= 1){
        if (tid < 4) spin_ge(&cnts[CWI(i-1, tid)], TGT(i-1));
        asm volatile("" ::: "memory");
        __syncthreads();
      }

      // ---- B parts: w rows ----
      if (i < TT){
        const float* __restrict__ Whprev = Wh + (size_t)i*SLOTW;
        int k0 = wave*4, k1 = min(k0 + 4, 60);
        if (k1 > k0) gemv_seg(Whprev + k0*64, WL1 + (400+k0)*CB, k1-k0, bg4, cg2, acc1);
      }
      if (i >= 1){
        const float* __restrict__ Whcur = Wh + (size_t)i*SLOTW;
        int k0 = wave*4, k1 = min(k0 + 4, 60);
        if (k1 > k0) gemv_seg(Whcur + k0*64, WL2 + (800+k0)*CB, k1-k0, bg4, cg2, acc2);
      }

      // ---- reduce1 + pointwise1 + publish h1(i) ----
      if (i < TT){
        *(float4*)&PART[(wave*CB + cg2  )*64 + bg4] = make_float4(acc1[0],acc1[1],acc1[2],acc1[3]);
        *(float4*)&PART[(wave*CB + cg2+1)*64 + bg4] = make_float4(acc1[4],acc1[5],acc1[6],acc1[7]);
        __syncthreads();
        if (tid < 512){
          int c = tid>>6, b = tid&63; float s = 0.f;
          #pragma unroll
          for (int w16=0; w16<NWAVE; ++w16) s += PART[(w16*CB + c)*64 + b];
          GRED[c*64 + b] = s;
        }
        __syncthreads();
        if (tid < 128){
          int u = tid>>6, b = tid&63, j = 2*p + u;
          float gi = GRED[(0+u)*64+b] + BS1[0+u];
          float gf = GRED[(2+u)*64+b] + BS1[2+u];
          float gg = GRED[(4+u)*64+b] + BS1[4+u];
          float go = GRED[(6+u)*64+b] + BS1[6+u];
          float c_ = sigm(gf)*CS1[u*64+b] + sigm(gi)*tanhf(gg);
          float h_ = sigm(go)*tanhf(c_);
          CS1[u*64+b] = c_;
          st_agent(&H1t[(size_t)(i+1)*SLOT1 + j*64 + b], h_);       // publish h1(i)
          st_agent(&H1TT[(size_t)(i&1)*SLOTT + b*400 + j], h_);     // transposed copy
          if (i == TT-1){ outp[H0F_OFF + b*HIDN + j] = h_; outp[C0F_OFF + b*HIDN + j] = c_; }
        }
        __syncthreads();                     // drain publishes
        if (tid == 0) arrive(&cnts[CAI(i, p>>3)]);
      }

      // ---- reduce2 + pointwise2 + publish h2(i-1) ----
      if (i >= 1){
        if (i >= TT) __syncthreads();        // PART ordering when reduce1 skipped
        *(float4*)&PART[(wave*CB + cg2  )*64 + bg4] = make_float4(acc2[0],acc2[1],acc2[2],acc2[3]);
        *(float4*)&PART[(wave*CB + cg2+1)*64 + bg4] = make_float4(acc2[4],acc2[5],acc2[6],acc2[7]);
        __syncthreads();
        if (tid < 512){
          int c = tid>>6, b = tid&63; float s = 0.f;
          #pragma unroll
          for (int w16=0; w16<NWAVE; ++w16) s += PART[(w16*CB + c)*64 + b];
          GRED[c*64 + b] = s;
        }
        __syncthreads();
        if (tid < 128){
          int u = tid>>6, b = tid&63, j = 2*p + u;
          float gi = GRED[(0+u)*64+b] + BS2[0+u];
          float gf = GRED[(2+u)*64+b] + BS2[2+u];
          float gg = GRED[(4+u)*64+b] + BS2[4+u];
          float go = GRED[(6+u)*64+b] + BS2[6+u];
          float c_ = sigm(gf)*CS2[u*64+b] + sigm(gi)*tanhf(gg);
          float h_ = sigm(go)*tanhf(c_);
          CS2[u*64+b] = c_;
          st_agent(&H2t[(size_t)i*SLOT1 + j*64 + b], h_);           // publish h2(i-1)
          if (i == TT){ outp[H1F_OFF + b*HIDN + j] = h_; outp[C1F_OFF + b*HIDN + j] = c_; }
        }
        if (i < TT){
          __syncthreads();                   // drain h2 publish
          if (tid == 0) arrive(&cnts[CHI(i-1, p>>3)]);
        }
      }
    }
  } else {
    // ================= WINDOW BLOCK (2 batches) =================
    const int wb = p - PBLK;
    const int b0 = wb * WBAT;
    float* WWT = SM + S_WWT;  float* ONE = SM + S_ONE;
    float* H1S = SM + S_H1S;  float* TMS = SM + S_TMS;
    float* PW  = SM + S_PW;   float* KAP = SM + S_KAP;
    float* PHI = SM + S_PHI;

    for (int idx = tid; idx < 30*400; idx += THR){
      int j = idx/400, k = idx - j*400;
      WWT[k*33 + j] = Wwin[idx];
    }
    for (int idx = tid; idx < WBAT*UU*DD; idx += THR) ONE[idx] = onehots[b0*(UU*DD) + idx];
    if (tid < WBAT*UU) TMS[tid] = tmask[b0*UU + tid];
    if (tid < WBAT*16) KAP[tid] = 0.f;
    __syncthreads();

    for (int i = 0; i < TT; ++i){
      if (tid < 25) spin_ge(&cnts[CAI(i, tid)], TGT(i));
      asm volatile("" ::: "memory");
      __syncthreads();
      // stage h1(i) from transposed ring: 2 contiguous 1600B rows
      const float* __restrict__ H1row = H1TT + (size_t)(i&1)*SLOTT;
      if (tid < 800){
        int bb = tid / 400, k = tid - bb*400;
        H1S[k*3 + bb] = H1row[(b0+bb)*400 + k];
      }
      __syncthreads();
      // dots: 960 threads = 60 (b,j) pairs x 16-way k split
      if (tid < 960){
        int ks = tid & 15, pair = tid >> 4;
        int b = pair / 30, j = pair - b*30;
        float s = 0.f;
        #pragma unroll
        for (int kk = 0; kk < 25; ++kk){
          int k = ks*25 + kk;
          s = fmaf(H1S[k*3 + b], WWT[k*33 + j], s);
        }
        s += __shfl_down(s, 8, 16);
        s += __shfl_down(s, 4, 16);
        s += __shfl_down(s, 2, 16);
        s += __shfl_down(s, 1, 16);
        if (ks == 0) PW[b*32 + j] = expf(s + bwin[j]);
      }
      __syncthreads();
      if (tid < WBAT*KK){
        int b = tid/KK, k = tid - b*KK;
        KAP[b*16 + k] += PW[b*32 + 20 + k];
      }
      __syncthreads();
      // phi: 128 threads (b,u)
      if (tid < WBAT*UU){
        int b = tid >> 6, u = tid & 63;
        float uf = (float)u, s = 0.f;
        #pragma unroll
        for (int q = 0; q < KK; ++q){
          float d = KAP[b*16 + q] - uf;
          s = fmaf(PW[b*32 + q], expf(-PW[b*32 + 10 + q]*d*d), s);
        }
        s *= TMS[b*64 + u];
        PHI[b*64 + u] = s;
        if (i == TT-1) outp[PHI_OFF + (b0+b)*UU + u] = s;
      }
      __syncthreads();
      // w: 120 threads (b,d)
      if (tid < WBAT*DD){
        int b = tid/DD, d = tid - b*DD;
        float s = 0.f;
        #pragma unroll 8
        for (int u = 0; u < UU; ++u) s = fmaf(PHI[b*64 + u], ONE[b*(UU*DD) + u*DD + d], s);
        st_agent(&Wh[(size_t)(i+1)*SLOTW + d*64 + b0 + b], s);  // publish w(i)
        if (i == TT-1) outp[WF_OFF + (b0+b)*DD + d] = s;
      }
      if (i == TT-1 && tid < WBAT*KK){
        int b = tid/KK, k = tid - b*KK;
        outp[KAPPA_OFF + (b0+b)*KK + k] = KAP[b*16 + k];
      }
      __syncthreads();                       // drain w publish
      if (tid == 0) arrive(&cnts[CWI(i, wb>>3)]);
    }
  }
}

// ---------- FC + heads: one block per timestep ----------
__global__ __launch_bounds__(128) void fc2_kernel(
    const float* __restrict__ H1t, const float* __restrict__ H2t,
    const float* __restrict__ WfcT, const float* __restrict__ bfc,
    float* __restrict__ outp)
{
  const int t   = blockIdx.x;
  const int tid = threadIdx.x;
  __shared__ float Xs[8][64];
  __shared__ float OUT[FCOUT][65];
  float acc[64];
  #pragma unroll
  for (int b=0;b<64;++b) acc[b]=0.f;
  const float* __restrict__ base1 = H1t + (size_t)(t+1)*SLOT1;
  const float* __restrict__ base2 = H2t + (size_t)(t+1)*SLOT1;

  for (int kb=0; kb<100; ++kb){
    __syncthreads();
    #pragma unroll
    for (int e=0;e<4;++e){
      int idx = e*128 + tid;
      int row = idx>>6, b = idx&63;
      int k = kb*8 + row;
      Xs[row][b] = (k<400) ? base1[k*64+b] : base2[(k-400)*64+b];
    }
    __syncthreads();
    if (tid < FCOUT){
      #pragma unroll
      for (int kk=0;kk<8;++kk){
        float wv = WfcT[(kb*8+kk)*FCOUT + tid];
        #pragma unroll
        for (int b4=0;b4<16;++b4){
          float4 xv = *(const float4*)&Xs[kk][b4*4];
          acc[b4*4+0] = fmaf(wv, xv.x, acc[b4*4+0]);
          acc[b4*4+1] = fmaf(wv, xv.y, acc[b4*4+1]);
          acc[b4*4+2] = fmaf(wv, xv.z, acc[b4*4+2]);
          acc[b4*4+3] = fmaf(wv, xv.w, acc[b4*4+3]);
        }
      }
    }
  }
  if (tid < FCOUT){
    float bj = bfc[tid];
    #pragma unroll
    for (int b=0;b<64;++b) OUT[tid][b] = acc[b] + bj;
  }
  __syncthreads();
  if (tid < 64){
    const int b = tid;
    const size_t pos = (size_t)b*TT + t;
    for (int j=0;j<40;++j) outp[MU_OFF  + pos*40 + j] = OUT[j][b];
    for (int j=0;j<40;++j) outp[SIG_OFF + pos*40 + j] = OUT[40+j][b];
    float m = -1e30f;
    for (int q=0;q<20;++q) m = fmaxf(m, OUT[80+q][b]);
    float e[20], s=0.f;
    for (int q=0;q<20;++q){ e[q]=expf(OUT[80+q][b]-m); s+=e[q]; }
    float inv = 1.f/s;
    for (int q=0;q<20;++q) outp[PI_OFF  + pos*20 + q] = e[q]*inv;
    for (int q=0;q<20;++q) outp[RHO_OFF + pos*20 + q] = tanhf(OUT[100+q][b]);
    outp[EOS_OFF + pos] = 1.0f/(1.0f + expf(OUT[120][b]));
  }
}

extern "C" void kernel_launch(void* const* d_in, const int* in_sizes, int n_in,
                              void* d_out, int out_size, void* d_ws, size_t ws_size,
                              hipStream_t stream){
  (void)in_sizes; (void)n_in; (void)out_size; (void)ws_size;
  const float* strokes = (const float*)d_in[0];
  const float* onehots = (const float*)d_in[1];
  const float* tmask   = (const float*)d_in[2];
  const float* Wih1    = (const float*)d_in[3];
  const float* Whh1    = (const float*)d_in[4];
  const float* b1      = (const float*)d_in[5];
  const float* Wwin    = (const float*)d_in[6];
  const float* bwin    = (const float*)d_in[7];
  const float* Wih2    = (const float*)d_in[8];
  const float* Whh2    = (const float*)d_in[9];
  const float* b2      = (const float*)d_in[10];
  const float* Wfc     = (const float*)d_in[11];
  const float* bfc     = (const float*)d_in[12];

  float* ws    = (float*)d_ws;
  float* outp  = (float*)d_out;
  float* H1t   = ws + WS_H1T;
  float* H2t   = ws + WS_H2T;
  float* Wh    = ws + WS_WHT;
  float* XST   = ws + WS_XST;
  float* WALL1 = ws + WS_WALL1;
  float* WALL2 = ws + WS_WALL2;
  float* WfcT  = ws + WS_WFCT;
  int*   cnts  = (int*)(ws + WS_CNT);
  float* H1TT  = ws + WS_H1TT;

  hipLaunchKernelGGL(prep_init, dim3((TT*3*64 + 255)/256), dim3(256), 0, stream,
                     onehots, strokes, H1t, H2t, Wh, XST, cnts);
  hipLaunchKernelGGL(prep_wall, dim3((2121600 + 255)/256), dim3(256), 0, stream,
                     Wih1, Whh1, Wih2, Whh2, WALL1, WALL2);
  hipLaunchKernelGGL(prep_wfc, dim3((FCIN*FCOUT + 255)/256), dim3(256), 0, stream,
                     Wfc, WfcT);

  hipLaunchKernelGGL(recurrent_kernel, dim3(TOTB), dim3(THR), 0, stream,
                     Wwin, bwin, b1, b2, tmask, onehots, WALL1, WALL2,
                     H1t, H2t, Wh, XST, H1TT, cnts, outp);

  hipLaunchKernelGGL(fc2_kernel, dim3(TT), dim3(128), 0, stream,
                     H1t, H2t, WfcT, bfc, outp);
}

// Round 10
// 8337.545 us; speedup vs baseline: 2.5221x; 1.0720x over previous
//
#include <hip/hip_runtime.h>
#include <hip/hip_bf16.h>
#include <math.h>

#define HIDN 400
#define KK   10
#define UU   64
#define DD   60
#define TT   600
#define BB   64
#define FCIN 800
#define FCOUT 121

#define PBLK 200      // unit blocks (2 hidden units of both LSTMs each)
#define NWBK 32       // window blocks (2 batches each)
#define WBAT 2
#define TOTB (PBLK + NWBK)
#define THR  1024     // 16 waves
#define NWAVE 16
#define CB   8        // gate-cols per unit block per LSTM

#define SLOT1 25600   // 400*64
#define SLOTW 3840    // 60*64

// ---- d_out offsets (floats) ----
#define PI_OFF    0
#define MU_OFF    768000
#define SIG_OFF   2304000
#define RHO_OFF   3840000
#define EOS_OFF   4608000
#define WF_OFF    4646400
#define KAPPA_OFF 4650240
#define PHI_OFF   4650880
#define H0F_OFF   4654976
#define C0F_OFF   4680576
#define H1F_OFF   4706176
#define C1F_OFF   4731776

// ---- workspace offsets (floats) ----
#define WS_H1T   0                  // 601*25600
#define WS_H2T   15385600           // 601*25600
#define WS_WHT   30771200           // 601*3840
#define WS_XST   33079040           // 600*3*64
#define WS_WALL1 33194240           // 200*463*8
#define WS_WALL2 33935040           // 200*863*8
#define WS_WFCT  35315840           // 800*121
#define WS_CNT   35412640           // 6912 ints
// total ~= 35,419,552 floats = 141.7 MB

// ---- grouped barrier counters (8 arrivals/line, modulo-8 window, monotone) ----
#define CAI(i,g) ((((i)&7)*25+(g))*16)            // h1: 25 groups of 8 unit blocks
#define CWI(i,g) (3200 + (((i)&7)*4+(g))*16)      // w : 4 groups of 8 window blocks
#define CHI(i,g) (3712 + (((i)&7)*25+(g))*16)     // h2: 25 groups
#define CNT_INTS 6912
#define TGT(i)   ((((i)>>3)+1)*8)

// ---- LDS layout (floats), unit/window overlaid ----
#define S_WL1   0        // 3704  unit
#define S_WL2   3704     // 6904
#define S_PART  10608    // 8192
#define S_GRED  18800    // 512
#define S_CS1   19312    // 128
#define S_CS2   19440    // 128
#define S_BS1   19568    // 8
#define S_BS2   19576    // 8   -> unit end 19584
#define S_WWT   0        // 13200 window (Wwin transposed, stride 33)
#define S_ONE   13200    // 7680  (2 batches' onehots)
#define S_H1S   20880    // 1200  (h1 tile [400][3])
#define S_TMS   22080    // 128
#define S_PW    22208    // 64    ([2][32])
#define S_KAP   22272    // 32    ([2][16])
#define S_PHI   22304    // 128   ([2][64])
#define SMEM_F  22432    // 89.7 KB -> 1 block/CU

__device__ __forceinline__ float sigm(float x){ return 1.0f/(1.0f + expf(-x)); }

__device__ __forceinline__ void st_agent(float* p, float v){
  __hip_atomic_store(p, v, __ATOMIC_RELAXED, __HIP_MEMORY_SCOPE_AGENT);
}
__device__ __forceinline__ int ld_agent_i(const int* p){
  return __hip_atomic_load(p, __ATOMIC_RELAXED, __HIP_MEMORY_SCOPE_AGENT);
}
__device__ __forceinline__ void arrive(int* p){
  __hip_atomic_fetch_add(p, 1, __ATOMIC_RELAXED, __HIP_MEMORY_SCOPE_AGENT);
}
__device__ __forceinline__ void spin_ge(const int* w, int tgt){
  if (ld_agent_i(w) >= tgt) return;
  do { __builtin_amdgcn_s_sleep(1); } while (ld_agent_i(w) < tgt);
}

// ---------- prep ----------
__global__ void prep_init(const float* __restrict__ onehots, const float* __restrict__ strokes,
                          float* __restrict__ H1t, float* __restrict__ H2t,
                          float* __restrict__ Wh,  float* __restrict__ XST,
                          int* __restrict__ cnts){
  int idx = blockIdx.x*blockDim.x + threadIdx.x;
  if (idx < SLOT1){ H1t[idx] = 0.f; H2t[idx] = 0.f; }
  if (idx < SLOTW){
    int d = idx >> 6, b = idx & 63;
    Wh[idx] = onehots[b*(UU*DD) + d];            // onehots[b, u=0, d]
  }
  if (idx < TT*3*64){
    int t = idx/192, rem = idx%192, comp = rem/64, b = rem%64;
    XST[idx] = strokes[(b*TT + t)*3 + comp];
  }
  if (idx < CNT_INTS) cnts[idx] = 0;
}

// ---------- weight reorder (CB=8 both LSTMs) ----------
// unit block p owns hidden units {2p,2p+1}; col c = 2*q + (j&1); gates q: 0=i,1=f,2=g,3=o
// WALL1 rows: [0,400)=h1, [400,460)=w, [460,463)=x
// WALL2 rows: [0,400)=h1, [400,800)=h2, [800,860)=w, [860,863)=x
__global__ void prep_wall(const float* __restrict__ Wih1, const float* __restrict__ Whh1,
                          const float* __restrict__ Wih2, const float* __restrict__ Whh2,
                          float* __restrict__ WALL1, float* __restrict__ WALL2){
  int idx = blockIdx.x*blockDim.x + threadIdx.x;
  if (idx < 640000){                       // W_hh1 (1600,400)
    int g = idx/400, k = idx%400;
    int q = g/400, j = g%400, p = j>>1, c = 2*q + (j&1);
    WALL1[(p*463 + k)*CB + c] = Whh1[idx];
  } else if (idx < 740800){                // W_ih1 (1600,63)
    int s = idx - 640000;
    int g = s/63, col = s%63;
    int q = g/400, j = g%400, p = j>>1, c = 2*q + (j&1);
    int r = (col < 3) ? (460 + col) : (400 + col - 3);
    WALL1[(p*463 + r)*CB + c] = Wih1[s];
  } else if (idx < 1380800){               // W_hh2 (1600,400)
    int s = idx - 740800;
    int g = s/400, k = s%400;
    int q = g/400, j = g%400, p = j>>1, c = 2*q + (j&1);
    WALL2[(p*863 + 400 + k)*CB + c] = Whh2[s];
  } else if (idx < 2121600){               // W_ih2 (1600,463)
    int s = idx - 1380800;
    int g = s/463, col = s%463;
    int q = g/400, j = g%400, p = j>>1, c = 2*q + (j&1);
    int r = (col<3) ? (860+col) : (col<63 ? (800+col-3) : (col-63));
    WALL2[(p*863 + r)*CB + c] = Wih2[s];
  }
}

__global__ void prep_wfc(const float* __restrict__ Wfc, float* __restrict__ WfcT){
  int idx = blockIdx.x*blockDim.x + threadIdx.x;
  if (idx >= FCIN*FCOUT) return;
  int k = idx / FCOUT, j = idx - k*FCOUT;
  WfcT[idx] = Wfc[j*FCIN + k];
}

// ---------- GEMV segment ----------
__device__ __forceinline__ void gemv_seg(const float* __restrict__ x,
                                         const float* __restrict__ w,
                                         int n, int bg4, int cg2, float acc[8]){
  #pragma unroll 4
  for (int k=0;k<n;++k){
    const float4 xv = *(const float4*)(x + k*64 + bg4);
    const float2 wv = *(const float2*)(w + k*CB + cg2);
    acc[0] = fmaf(wv.x, xv.x, acc[0]);
    acc[1] = fmaf(wv.x, xv.y, acc[1]);
    acc[2] = fmaf(wv.x, xv.z, acc[2]);
    acc[3] = fmaf(wv.x, xv.w, acc[3]);
    acc[4] = fmaf(wv.y, xv.x, acc[4]);
    acc[5] = fmaf(wv.y, xv.y, acc[5]);
    acc[6] = fmaf(wv.y, xv.z, acc[6]);
    acc[7] = fmaf(wv.y, xv.w, acc[7]);
  }
}

// ---------- persistent recurrent kernel ----------
__global__ __launch_bounds__(THR) void recurrent_kernel(
    const float* __restrict__ Wwin, const float* __restrict__ bwin,
    const float* __restrict__ b1g,  const float* __restrict__ b2g,
    const float* __restrict__ tmask,const float* __restrict__ onehots,
    const float* __restrict__ WALL1,const float* __restrict__ WALL2,
    float* __restrict__ H1t,        float* __restrict__ H2t,
    float* __restrict__ Wh,         const float* __restrict__ XST,
    int* __restrict__ cnts,         float* __restrict__ outp)
{
  const int p   = blockIdx.x;
  const int tid = threadIdx.x;
  __shared__ float SM[SMEM_F];

  if (p < PBLK){
    // ================= UNIT BLOCK =================
    const int wave = tid >> 6, lane = tid & 63;
    const int bg4  = (lane & 15) * 4;
    const int cg2  = (lane >> 4) * 2;
    float* WL1 = SM + S_WL1;  float* WL2 = SM + S_WL2;
    float* PART= SM + S_PART; float* GRED= SM + S_GRED;
    float* CS1 = SM + S_CS1;  float* CS2 = SM + S_CS2;
    float* BS1 = SM + S_BS1;  float* BS2 = SM + S_BS2;

    for (int idx = tid; idx < 463*CB; idx += THR) WL1[idx] = WALL1[p*463*CB + idx];
    for (int idx = tid; idx < 863*CB; idx += THR) WL2[idx] = WALL2[p*863*CB + idx];
    if (tid < CB){ int q = tid>>1, u = tid&1; int j = 2*p+u;
      BS1[tid] = b1g[q*HIDN + j]; BS2[tid] = b2g[q*HIDN + j]; }
    if (tid < 128){ CS1[tid] = 0.f; CS2[tid] = 0.f; }
    __syncthreads();

    for (int i = 0; i <= TT; ++i){
      // ---- wait CA(i-1): h1(i-1) ready ----
      if (i >= 1){
        if (tid < 25) spin_ge(&cnts[CAI(i-1, tid)], TGT(i-1));
        asm volatile("" ::: "memory");
        __syncthreads();
      }

      // ======== h1 chain first: GEMV1 + publish h1(i) ========
      if (i < TT){
        float acc1[8] = {0,0,0,0,0,0,0,0};
        // GEMV1-A: h1 rows [0,400) + x rows [460,463)
        {
          const float* __restrict__ H1prev = H1t + (size_t)i*SLOT1;
          int k0 = wave*26, k1 = min(k0 + 26, 403);
          { int ka = k0, kb = min(k1, 400);
            if (kb > ka) gemv_seg(H1prev + ka*64, WL1 + ka*CB, kb-ka, bg4, cg2, acc1); }
          { int ka = max(k0,400), kb = k1;
            if (kb > ka) gemv_seg(XST + i*192 + (ka-400)*64, WL1 + (460+ka-400)*CB, kb-ka, bg4, cg2, acc1); }
        }
        // wait CW(i-1): w(i-1) (window i-1 overlapped our previous GEMV2 — normally ready)
        if (i >= 1){
          if (tid < 4) spin_ge(&cnts[CWI(i-1, tid)], TGT(i-1));
          asm volatile("" ::: "memory");
          __syncthreads();
        }
        // GEMV1-B: w rows [400,460)
        {
          const float* __restrict__ Whprev = Wh + (size_t)i*SLOTW;
          int k0 = wave*4, k1 = min(k0 + 4, 60);
          if (k1 > k0) gemv_seg(Whprev + k0*64, WL1 + (400+k0)*CB, k1-k0, bg4, cg2, acc1);
        }
        // reduce + pointwise + publish h1(i)
        *(float4*)&PART[(wave*CB + cg2  )*64 + bg4] = make_float4(acc1[0],acc1[1],acc1[2],acc1[3]);
        *(float4*)&PART[(wave*CB + cg2+1)*64 + bg4] = make_float4(acc1[4],acc1[5],acc1[6],acc1[7]);
        __syncthreads();
        if (tid < 512){
          int c = tid>>6, b = tid&63; float s = 0.f;
          #pragma unroll
          for (int w16=0; w16<NWAVE; ++w16) s += PART[(w16*CB + c)*64 + b];
          GRED[c*64 + b] = s;
        }
        __syncthreads();
        if (tid < 128){
          int u = tid>>6, b = tid&63, j = 2*p + u;
          float gi = GRED[(0+u)*64+b] + BS1[0+u];
          float gf = GRED[(2+u)*64+b] + BS1[2+u];
          float gg = GRED[(4+u)*64+b] + BS1[4+u];
          float go = GRED[(6+u)*64+b] + BS1[6+u];
          float c_ = sigm(gf)*CS1[u*64+b] + sigm(gi)*tanhf(gg);
          float h_ = sigm(go)*tanhf(c_);
          CS1[u*64+b] = c_;
          st_agent(&H1t[(size_t)(i+1)*SLOT1 + j*64 + b], h_);       // publish h1(i)
          if (i == TT-1){ outp[H0F_OFF + b*HIDN + j] = h_; outp[C0F_OFF + b*HIDN + j] = c_; }
        }
        __syncthreads();                     // drain publish
        if (tid == 0) arrive(&cnts[CAI(i, p>>3)]);
      }

      // ======== shadow work: GEMV2 (step i-1) + publish h2(i-1) ========
      if (i >= 1){
        if (i >= 2){
          if (tid < 25) spin_ge(&cnts[CHI(i-2, tid)], TGT(i-2));
          asm volatile("" ::: "memory");
          __syncthreads();
        }
        const int t2 = i - 1;
        const float* __restrict__ H1cur = H1t + (size_t)i*SLOT1;
        const float* __restrict__ H2pp  = H2t + (size_t)(i-1)*SLOT1;
        const float* __restrict__ Whcur = Wh  + (size_t)i*SLOTW;
        float acc2[8] = {0,0,0,0,0,0,0,0};
        int k0 = wave*54, k1 = min(k0 + 54, 863);
        { int ka = k0, kb = min(k1, 400);
          if (kb > ka) gemv_seg(H1cur + ka*64, WL2 + ka*CB, kb-ka, bg4, cg2, acc2); }
        { int ka = max(k0,400), kb = min(k1, 800);
          if (kb > ka) gemv_seg(H2pp + (ka-400)*64, WL2 + ka*CB, kb-ka, bg4, cg2, acc2); }
        { int ka = max(k0,800), kb = min(k1, 860);
          if (kb > ka) gemv_seg(Whcur + (ka-800)*64, WL2 + ka*CB, kb-ka, bg4, cg2, acc2); }
        { int ka = max(k0,860), kb = k1;
          if (kb > ka) gemv_seg(XST + t2*192 + (ka-860)*64, WL2 + ka*CB, kb-ka, bg4, cg2, acc2); }
        __syncthreads();                     // PART free (reduce1 readers done)
        *(float4*)&PART[(wave*CB + cg2  )*64 + bg4] = make_float4(acc2[0],acc2[1],acc2[2],acc2[3]);
        *(float4*)&PART[(wave*CB + cg2+1)*64 + bg4] = make_float4(acc2[4],acc2[5],acc2[6],acc2[7]);
        __syncthreads();
        if (tid < 512){
          int c = tid>>6, b = tid&63; float s = 0.f;
          #pragma unroll
          for (int w16=0; w16<NWAVE; ++w16) s += PART[(w16*CB + c)*64 + b];
          GRED[c*64 + b] = s;
        }
        __syncthreads();
        if (tid < 128){
          int u = tid>>6, b = tid&63, j = 2*p + u;
          float gi = GRED[(0+u)*64+b] + BS2[0+u];
          float gf = GRED[(2+u)*64+b] + BS2[2+u];
          float gg = GRED[(4+u)*64+b] + BS2[4+u];
          float go = GRED[(6+u)*64+b] + BS2[6+u];
          float c_ = sigm(gf)*CS2[u*64+b] + sigm(gi)*tanhf(gg);
          float h_ = sigm(go)*tanhf(c_);
          CS2[u*64+b] = c_;
          st_agent(&H2t[(size_t)i*SLOT1 + j*64 + b], h_);           // publish h2(i-1)
          if (i == TT){ outp[H1F_OFF + b*HIDN + j] = h_; outp[C1F_OFF + b*HIDN + j] = c_; }
        }
        if (i < TT){
          __syncthreads();                   // drain h2 publish
          if (tid == 0) arrive(&cnts[CHI(i-1, p>>3)]);
        }
      }
    }
  } else {
    // ================= WINDOW BLOCK (2 batches) =================
    const int wb = p - PBLK;
    const int b0 = wb * WBAT;
    float* WWT = SM + S_WWT;  float* ONE = SM + S_ONE;
    float* H1S = SM + S_H1S;  float* TMS = SM + S_TMS;
    float* PW  = SM + S_PW;   float* KAP = SM + S_KAP;
    float* PHI = SM + S_PHI;

    for (int idx = tid; idx < 30*400; idx += THR){
      int j = idx/400, k = idx - j*400;
      WWT[k*33 + j] = Wwin[idx];
    }
    for (int idx = tid; idx < WBAT*UU*DD; idx += THR) ONE[idx] = onehots[b0*(UU*DD) + idx];
    if (tid < WBAT*UU) TMS[tid] = tmask[b0*UU + tid];
    if (tid < WBAT*16) KAP[tid] = 0.f;
    __syncthreads();

    for (int i = 0; i < TT; ++i){
      if (tid < 25) spin_ge(&cnts[CAI(i, tid)], TGT(i));
      asm volatile("" ::: "memory");
      __syncthreads();
      // stage h1(i) tile [400][WBAT] (pad 3)
      const float* __restrict__ H1now = H1t + (size_t)(i+1)*SLOT1;
      if (tid < 800){
        int bb = tid / 400, k = tid - bb*400;
        H1S[k*3 + bb] = H1now[k*64 + b0 + bb];
      }
      __syncthreads();
      // dots: 960 threads = 60 (b,j) pairs x 16-way k split
      if (tid < 960){
        int ks = tid & 15, pair = tid >> 4;
        int b = pair / 30, j = pair - b*30;
        float s = 0.f;
        #pragma unroll
        for (int kk = 0; kk < 25; ++kk){
          int k = ks*25 + kk;
          s = fmaf(H1S[k*3 + b], WWT[k*33 + j], s);
        }
        s += __shfl_down(s, 8, 16);
        s += __shfl_down(s, 4, 16);
        s += __shfl_down(s, 2, 16);
        s += __shfl_down(s, 1, 16);
        if (ks == 0) PW[b*32 + j] = expf(s + bwin[j]);
      }
      __syncthreads();
      if (tid < WBAT*KK){
        int b = tid/KK, k = tid - b*KK;
        KAP[b*16 + k] += PW[b*32 + 20 + k];
      }
      __syncthreads();
      // phi: 128 threads (b,u)
      if (tid < WBAT*UU){
        int b = tid >> 6, u = tid & 63;
        float uf = (float)u, s = 0.f;
        #pragma unroll
        for (int q = 0; q < KK; ++q){
          float d = KAP[b*16 + q] - uf;
          s = fmaf(PW[b*32 + q], expf(-PW[b*32 + 10 + q]*d*d), s);
        }
        s *= TMS[b*64 + u];
        PHI[b*64 + u] = s;
        if (i == TT-1) outp[PHI_OFF + (b0+b)*UU + u] = s;
      }
      __syncthreads();
      // w: 120 threads (b,d)
      if (tid < WBAT*DD){
        int b = tid/DD, d = tid - b*DD;
        float s = 0.f;
        #pragma unroll 8
        for (int u = 0; u < UU; ++u) s = fmaf(PHI[b*64 + u], ONE[b*(UU*DD) + u*DD + d], s);
        st_agent(&Wh[(size_t)(i+1)*SLOTW + d*64 + b0 + b], s);  // publish w(i)
        if (i == TT-1) outp[WF_OFF + (b0+b)*DD + d] = s;
      }
      if (i == TT-1 && tid < WBAT*KK){
        int b = tid/KK, k = tid - b*KK;
        outp[KAPPA_OFF + (b0+b)*KK + k] = KAP[b*16 + k];
      }
      __syncthreads();                       // drain w publish
      if (tid == 0) arrive(&cnts[CWI(i, wb>>3)]);
    }
  }
}

// ---------- FC + heads: one block per timestep ----------
__global__ __launch_bounds__(128) void fc2_kernel(
    const float* __restrict__ H1t, const float* __restrict__ H2t,
    const float* __restrict__ WfcT, const float* __restrict__ bfc,
    float* __restrict__ outp)
{
  const int t   = blockIdx.x;
  const int tid = threadIdx.x;
  __shared__ float Xs[8][64];
  __shared__ float OUT[FCOUT][65];
  float acc[64];
  #pragma unroll
  for (int b=0;b<64;++b) acc[b]=0.f;
  const float* __restrict__ base1 = H1t + (size_t)(t+1)*SLOT1;
  const float* __restrict__ base2 = H2t + (size_t)(t+1)*SLOT1;

  for (int kb=0; kb<100; ++kb){
    __syncthreads();
    #pragma unroll
    for (int e=0;e<4;++e){
      int idx = e*128 + tid;
      int row = idx>>6, b = idx&63;
      int k = kb*8 + row;
      Xs[row][b] = (k<400) ? base1[k*64+b] : base2[(k-400)*64+b];
    }
    __syncthreads();
    if (tid < FCOUT){
      #pragma unroll
      for (int kk=0;kk<8;++kk){
        float wv = WfcT[(kb*8+kk)*FCOUT + tid];
        #pragma unroll
        for (int b4=0;b4<16;++b4){
          float4 xv = *(const float4*)&Xs[kk][b4*4];
          acc[b4*4+0] = fmaf(wv, xv.x, acc[b4*4+0]);
          acc[b4*4+1] = fmaf(wv, xv.y, acc[b4*4+1]);
          acc[b4*4+2] = fmaf(wv, xv.z, acc[b4*4+2]);
          acc[b4*4+3] = fmaf(wv, xv.w, acc[b4*4+3]);
        }
      }
    }
  }
  if (tid < FCOUT){
    float bj = bfc[tid];
    #pragma unroll
    for (int b=0;b<64;++b) OUT[tid][b] = acc[b] + bj;
  }
  __syncthreads();
  if (tid < 64){
    const int b = tid;
    const size_t pos = (size_t)b*TT + t;
    for (int j=0;j<40;++j) outp[MU_OFF  + pos*40 + j] = OUT[j][b];
    for (int j=0;j<40;++j) outp[SIG_OFF + pos*40 + j] = OUT[40+j][b];
    float m = -1e30f;
    for (int q=0;q<20;++q) m = fmaxf(m, OUT[80+q][b]);
    float e[20], s=0.f;
    for (int q=0;q<20;++q){ e[q]=expf(OUT[80+q][b]-m); s+=e[q]; }
    float inv = 1.f/s;
    for (int q=0;q<20;++q) outp[PI_OFF  + pos*20 + q] = e[q]*inv;
    for (int q=0;q<20;++q) outp[RHO_OFF + pos*20 + q] = tanhf(OUT[100+q][b]);
    outp[EOS_OFF + pos] = 1.0f/(1.0f + expf(OUT[120][b]));
  }
}

extern "C" void kernel_launch(void* const* d_in, const int* in_sizes, int n_in,
                              void* d_out, int out_size, void* d_ws, size_t ws_size,
                              hipStream_t stream){
  (void)in_sizes; (void)n_in; (void)out_size; (void)ws_size;
  const float* strokes = (const float*)d_in[0];
  const float* onehots = (const float*)d_in[1];
  const float* tmask   = (const float*)d_in[2];
  const float* Wih1    = (const float*)d_in[3];
  const float* Whh1    = (const float*)d_in[4];
  const float* b1      = (const float*)d_in[5];
  const float* Wwin    = (const float*)d_in[6];
  const float* bwin    = (const float*)d_in[7];
  const float* Wih2    = (const float*)d_in[8];
  const float* Whh2    = (const float*)d_in[9];
  const float* b2      = (const float*)d_in[10];
  const float* Wfc     = (const float*)d_in[11];
  const float* bfc     = (const float*)d_in[12];

  float* ws    = (float*)d_ws;
  float* outp  = (float*)d_out;
  float* H1t   = ws + WS_H1T;
  float* H2t   = ws + WS_H2T;
  float* Wh    = ws + WS_WHT;
  float* XST   = ws + WS_XST;
  float* WALL1 = ws + WS_WALL1;
  float* WALL2 = ws + WS_WALL2;
  float* WfcT  = ws + WS_WFCT;
  int*   cnts  = (int*)(ws + WS_CNT);

  hipLaunchKernelGGL(prep_init, dim3((TT*3*64 + 255)/256), dim3(256), 0, stream,
                     onehots, strokes, H1t, H2t, Wh, XST, cnts);
  hipLaunchKernelGGL(prep_wall, dim3((2121600 + 255)/256), dim3(256), 0, stream,
                     Wih1, Whh1, Wih2, Whh2, WALL1, WALL2);
  hipLaunchKernelGGL(prep_wfc, dim3((FCIN*FCOUT + 255)/256), dim3(256), 0, stream,
                     Wfc, WfcT);

  hipLaunchKernelGGL(recurrent_kernel, dim3(TOTB), dim3(THR), 0, stream,
                     Wwin, bwin, b1, b2, tmask, onehots, WALL1, WALL2,
                     H1t, H2t, Wh, XST, cnts, outp);

  hipLaunchKernelGGL(fc2_kernel, dim3(TT), dim3(128), 0, stream,
                     H1t, H2t, WfcT, bfc, outp);
}

// Round 11
// 7326.862 us; speedup vs baseline: 2.8701x; 1.1379x over previous
//
#include <hip/hip_runtime.h>
#include <hip/hip_bf16.h>
#include <math.h>

#define HIDN 400
#define KK   10
#define UU   64
#define DD   60
#define TT   600
#define FCIN 800
#define FCOUT 121

#define NH1  100      // h1 blocks (4 units each)
#define NH2  100      // h2 blocks (4 units each)
#define NWBK 32       // window blocks (2 batches each)
#define WBAT 2
#define TOTB 232
#define THR  1024
#define NWAVE 16
#define CB   16       // gate-cols per block (4 units x 4 gates)
#define PSTR 68       // padded PART row stride

#define SLOT1 25600   // 400*64
#define SLOTW 3840    // 60*64

// ---- d_out offsets (floats) ----
#define PI_OFF    0
#define MU_OFF    768000
#define SIG_OFF   2304000
#define RHO_OFF   3840000
#define EOS_OFF   4608000
#define WF_OFF    4646400
#define KAPPA_OFF 4650240
#define PHI_OFF   4650880
#define H0F_OFF   4654976
#define C0F_OFF   4680576
#define H1F_OFF   4706176
#define C1F_OFF   4731776

// ---- workspace offsets (floats) ----
#define WS_H1T   0                  // 601*25600
#define WS_H2T   15385600           // 601*25600
#define WS_WHT   30771200           // 601*3840
#define WS_XST   33079040           // 600*3*64
#define WS_WALL1 33194240           // 100*463*16 = 740,800
#define WS_WALL2 33935040           // 100*863*16 = 1,380,800
#define WS_WFCT  35315840           // 800*121
#define WS_CNT   35412640           // 3840 ints
// total ~= 35,416,480 floats = 141.7 MB

// ---- grouped barrier counters (mod-8 ring, monotone) ----
#define CAI(i,g) ((((i)&7)*13+(g))*16)            // h1: 13 groups (12x8 + 1x4)
#define CWI(i,g) (1664 + (((i)&7)*4+(g))*16)      // w : 4 groups of 8
#define CHI(i,g) (2176 + (((i)&7)*13+(g))*16)     // h2: 13 groups
#define CNT_INTS 3840

// ---- LDS layout (floats), role-overlaid ----
// h1 role: WL1@0(7408) PART@7408(17408) GRED@24816(1024) CS@25840(256) BS@26096(16)
// h2 role: WL2@0(13808) PART@13808(17408) GRED@31216(1024) CS@32240(256) BS@32496(16)
// win role: WWT@0(13200) ONE@13200(7680) H1S@20880(1200) TMS@22080(128)
//           PW@22208(64) KAP@22272(32) PHI@22304(128)
#define SMEM_F 32512   // 130 KB -> 1 block/CU

__device__ __forceinline__ float sigm(float x){ return 1.0f/(1.0f + expf(-x)); }
__device__ __forceinline__ int tgtn(int i, int n){ return n*((i>>3)+1); }

__device__ __forceinline__ void st_agent(float* p, float v){
  __hip_atomic_store(p, v, __ATOMIC_RELAXED, __HIP_MEMORY_SCOPE_AGENT);
}
__device__ __forceinline__ int ld_agent_i(const int* p){
  return __hip_atomic_load(p, __ATOMIC_RELAXED, __HIP_MEMORY_SCOPE_AGENT);
}
__device__ __forceinline__ void arrive(int* p){
  __hip_atomic_fetch_add(p, 1, __ATOMIC_RELAXED, __HIP_MEMORY_SCOPE_AGENT);
}
__device__ __forceinline__ void spin_ge(const int* w, int tgt){
  if (ld_agent_i(w) >= tgt) return;
  do { __builtin_amdgcn_s_sleep(1); } while (ld_agent_i(w) < tgt);
}

// ---------- prep ----------
__global__ void prep_init(const float* __restrict__ onehots, const float* __restrict__ strokes,
                          float* __restrict__ H1t, float* __restrict__ H2t,
                          float* __restrict__ Wh,  float* __restrict__ XST,
                          int* __restrict__ cnts){
  int idx = blockIdx.x*blockDim.x + threadIdx.x;
  if (idx < SLOT1){ H1t[idx] = 0.f; H2t[idx] = 0.f; }
  if (idx < SLOTW){
    int d = idx >> 6, b = idx & 63;
    Wh[idx] = onehots[b*(UU*DD) + d];            // onehots[b, u=0, d]
  }
  if (idx < TT*3*64){
    int t = idx/192, rem = idx%192, comp = rem/64, b = rem%64;
    XST[idx] = strokes[(b*TT + t)*3 + comp];
  }
  if (idx < CNT_INTS) cnts[idx] = 0;
}

// ---------- weight reorder: block owns units {4p..4p+3}; col c = 4*q + (j&3) ----------
// WALL1 rows: [0,400)=h1, [400,460)=w, [460,463)=x
// WALL2 rows: [0,400)=h1, [400,800)=h2, [800,860)=w, [860,863)=x
__global__ void prep_wall(const float* __restrict__ Wih1, const float* __restrict__ Whh1,
                          const float* __restrict__ Wih2, const float* __restrict__ Whh2,
                          float* __restrict__ WALL1, float* __restrict__ WALL2){
  int idx = blockIdx.x*blockDim.x + threadIdx.x;
  if (idx < 640000){                       // W_hh1 (1600,400)
    int g = idx/400, k = idx%400;
    int q = g/400, j = g%400, pp = j>>2, c = 4*q + (j&3);
    WALL1[((size_t)pp*463 + k)*CB + c] = Whh1[idx];
  } else if (idx < 740800){                // W_ih1 (1600,63)
    int s = idx - 640000;
    int g = s/63, col = s%63;
    int q = g/400, j = g%400, pp = j>>2, c = 4*q + (j&3);
    int r = (col < 3) ? (460 + col) : (400 + col - 3);
    WALL1[((size_t)pp*463 + r)*CB + c] = Wih1[s];
  } else if (idx < 1380800){               // W_hh2 (1600,400)
    int s = idx - 740800;
    int g = s/400, k = s%400;
    int q = g/400, j = g%400, pp = j>>2, c = 4*q + (j&3);
    WALL2[((size_t)pp*863 + 400 + k)*CB + c] = Whh2[s];
  } else if (idx < 2121600){               // W_ih2 (1600,463)
    int s = idx - 1380800;
    int g = s/463, col = s%463;
    int q = g/400, j = g%400, pp = j>>2, c = 4*q + (j&3);
    int r = (col<3) ? (860+col) : (col<63 ? (800+col-3) : (col-63));
    WALL2[((size_t)pp*863 + r)*CB + c] = Wih2[s];
  }
}

__global__ void prep_wfc(const float* __restrict__ Wfc, float* __restrict__ WfcT){
  int idx = blockIdx.x*blockDim.x + threadIdx.x;
  if (idx >= FCIN*FCOUT) return;
  int k = idx / FCOUT, j = idx - k*FCOUT;
  WfcT[idx] = Wfc[j*FCIN + k];
}

// ---------- GEMV segment: 16 cols ----------
__device__ __forceinline__ void gemv16(const float* __restrict__ x,
                                       const float* __restrict__ w,
                                       int n, int bg4, int cg4, float acc[16]){
  #pragma unroll 4
  for (int k=0;k<n;++k){
    const float4 xv = *(const float4*)(x + k*64 + bg4);
    const float4 wv = *(const float4*)(w + k*CB + cg4);
    acc[0]  = fmaf(wv.x, xv.x, acc[0]);
    acc[1]  = fmaf(wv.x, xv.y, acc[1]);
    acc[2]  = fmaf(wv.x, xv.z, acc[2]);
    acc[3]  = fmaf(wv.x, xv.w, acc[3]);
    acc[4]  = fmaf(wv.y, xv.x, acc[4]);
    acc[5]  = fmaf(wv.y, xv.y, acc[5]);
    acc[6]  = fmaf(wv.y, xv.z, acc[6]);
    acc[7]  = fmaf(wv.y, xv.w, acc[7]);
    acc[8]  = fmaf(wv.z, xv.x, acc[8]);
    acc[9]  = fmaf(wv.z, xv.y, acc[9]);
    acc[10] = fmaf(wv.z, xv.z, acc[10]);
    acc[11] = fmaf(wv.z, xv.w, acc[11]);
    acc[12] = fmaf(wv.w, xv.x, acc[12]);
    acc[13] = fmaf(wv.w, xv.y, acc[13]);
    acc[14] = fmaf(wv.w, xv.z, acc[14]);
    acc[15] = fmaf(wv.w, xv.w, acc[15]);
  }
}

// ---------- persistent recurrent kernel ----------
__global__ __launch_bounds__(THR) void recurrent_kernel(
    const float* __restrict__ Wwin, const float* __restrict__ bwin,
    const float* __restrict__ b1g,  const float* __restrict__ b2g,
    const float* __restrict__ tmask,const float* __restrict__ onehots,
    const float* __restrict__ WALL1,const float* __restrict__ WALL2,
    float* __restrict__ H1t,        float* __restrict__ H2t,
    float* __restrict__ Wh,         const float* __restrict__ XST,
    int* __restrict__ cnts,         float* __restrict__ outp)
{
  const int p   = blockIdx.x;
  const int tid = threadIdx.x;
  __shared__ float SM[SMEM_F];

  if (p < NH1){
    // ================= H1 BLOCK (units 4p..4p+3) =================
    const int wave = tid >> 6, lane = tid & 63;
    const int bg4  = (lane & 15) * 4;
    const int cg4  = (lane >> 4) * 4;
    float* WL1 = SM;          float* PART = SM + 7408;
    float* GRED= SM + 24816;  float* CS   = SM + 25840;
    float* BS  = SM + 26096;

    for (int idx = tid; idx < 463*CB; idx += THR) WL1[idx] = WALL1[(size_t)p*463*CB + idx];
    if (tid < 16){ int q = tid>>2, u = tid&3; BS[tid] = b1g[q*HIDN + 4*p + u]; }
    if (tid < 256) CS[tid] = 0.f;
    __syncthreads();

    for (int i = 0; i < TT; ++i){
      if (i >= 1){
        if (tid < 13) spin_ge(&cnts[CAI(i-1, tid)], tgtn(i-1, tid==12?4:8));
        asm volatile("" ::: "memory");
        __syncthreads();
      }
      float acc[16];
      #pragma unroll
      for (int z=0; z<16; ++z) acc[z] = 0.f;
      // A: h1(i-1) rows [0,400) + x(i) rows (WL1 460..462)
      {
        const float* __restrict__ H1prev = H1t + (size_t)i*SLOT1;
        int k0 = wave*26, k1 = min(k0 + 26, 403);
        { int ka = k0, kb = min(k1, 400);
          if (kb > ka) gemv16(H1prev + ka*64, WL1 + ka*CB, kb-ka, bg4, cg4, acc); }
        { int ka = max(k0,400), kb = k1;
          if (kb > ka) gemv16(XST + i*192 + (ka-400)*64, WL1 + (460+(ka-400))*CB, kb-ka, bg4, cg4, acc); }
      }
      // wait w(i-1)
      if (i >= 1){
        if (tid < 4) spin_ge(&cnts[CWI(i-1, tid)], tgtn(i-1, 8));
        asm volatile("" ::: "memory");
        __syncthreads();
      }
      // B: w rows [400,460)
      {
        const float* __restrict__ Whp = Wh + (size_t)i*SLOTW;
        int k0 = wave*4, k1 = min(k0 + 4, 60);
        if (k1 > k0) gemv16(Whp + k0*64, WL1 + (400+k0)*CB, k1-k0, bg4, cg4, acc);
      }
      // reduce + pointwise + publish h1(i)
      #pragma unroll
      for (int cc=0; cc<4; ++cc)
        *(float4*)&PART[(wave*16 + cg4 + cc)*PSTR + bg4] =
          make_float4(acc[cc*4+0], acc[cc*4+1], acc[cc*4+2], acc[cc*4+3]);
      __syncthreads();
      {
        int c = tid>>6, b = tid&63; float s = 0.f;
        #pragma unroll
        for (int w16=0; w16<NWAVE; ++w16) s += PART[(w16*16 + c)*PSTR + b];
        GRED[c*64 + b] = s;
      }
      __syncthreads();
      if (tid < 256){
        int u = tid>>6, b = tid&63, j = 4*p + u;
        float gi = GRED[( 0+u)*64+b] + BS[ 0+u];
        float gf = GRED[( 4+u)*64+b] + BS[ 4+u];
        float gg = GRED[( 8+u)*64+b] + BS[ 8+u];
        float go = GRED[(12+u)*64+b] + BS[12+u];
        float c_ = sigm(gf)*CS[u*64+b] + sigm(gi)*tanhf(gg);
        float h_ = sigm(go)*tanhf(c_);
        CS[u*64+b] = c_;
        st_agent(&H1t[(size_t)(i+1)*SLOT1 + j*64 + b], h_);
        if (i == TT-1){ outp[H0F_OFF + b*HIDN + j] = h_; outp[C0F_OFF + b*HIDN + j] = c_; }
      }
      __syncthreads();                       // drain publish
      if (tid == 0) arrive(&cnts[CAI(i, p>>3)]);
    }
  } else if (p < NH1 + NH2){
    // ================= H2 BLOCK (units 4q2..4q2+3) =================
    const int q2 = p - NH1;
    const int wave = tid >> 6, lane = tid & 63;
    const int bg4  = (lane & 15) * 4;
    const int cg4  = (lane >> 4) * 4;
    float* WL2 = SM;          float* PART = SM + 13808;
    float* GRED= SM + 31216;  float* CS   = SM + 32240;
    float* BS  = SM + 32496;

    for (int idx = tid; idx < 863*CB; idx += THR) WL2[idx] = WALL2[(size_t)q2*863*CB + idx];
    if (tid < 16){ int q = tid>>2, u = tid&3; BS[tid] = b2g[q*HIDN + 4*q2 + u]; }
    if (tid < 256) CS[tid] = 0.f;
    __syncthreads();

    for (int t2 = 0; t2 < TT; ++t2){
      // wait h1(t2), w(t2) — lagging pipeline, usually pre-satisfied
      if (tid < 13) spin_ge(&cnts[CAI(t2, tid)], tgtn(t2, tid==12?4:8));
      else if (tid >= 64 && tid < 68) spin_ge(&cnts[CWI(t2, tid-64)], tgtn(t2, 8));
      asm volatile("" ::: "memory");
      __syncthreads();
      float acc[16];
      #pragma unroll
      for (int z=0; z<16; ++z) acc[z] = 0.f;
      // A: h1(t2) [0,400), w(t2) [800,860), x(t2) [860,863)
      {
        const float* __restrict__ H1v = H1t + (size_t)(t2+1)*SLOT1;
        const float* __restrict__ Whv = Wh  + (size_t)(t2+1)*SLOTW;
        int k0 = wave*29, k1 = min(k0 + 29, 463);
        { int ka = k0, kb = min(k1, 400);
          if (kb > ka) gemv16(H1v + ka*64, WL2 + ka*CB, kb-ka, bg4, cg4, acc); }
        { int ka = max(k0,400), kb = min(k1, 460);
          if (kb > ka) gemv16(Whv + (ka-400)*64, WL2 + (800+(ka-400))*CB, kb-ka, bg4, cg4, acc); }
        { int ka = max(k0,460), kb = k1;
          if (kb > ka) gemv16(XST + t2*192 + (ka-460)*64, WL2 + (860+(ka-460))*CB, kb-ka, bg4, cg4, acc); }
      }
      // own chain: h2(t2-1)
      if (t2 >= 1){
        if (tid < 13) spin_ge(&cnts[CHI(t2-1, tid)], tgtn(t2-1, tid==12?4:8));
        asm volatile("" ::: "memory");
        __syncthreads();
      }
      // B: h2(t2-1) rows [400,800)
      {
        const float* __restrict__ H2v = H2t + (size_t)t2*SLOT1;
        int k0 = wave*25, k1 = min(k0 + 25, 400);
        if (k1 > k0) gemv16(H2v + k0*64, WL2 + (400+k0)*CB, k1-k0, bg4, cg4, acc);
      }
      // reduce + pointwise + publish h2(t2)
      #pragma unroll
      for (int cc=0; cc<4; ++cc)
        *(float4*)&PART[(wave*16 + cg4 + cc)*PSTR + bg4] =
          make_float4(acc[cc*4+0], acc[cc*4+1], acc[cc*4+2], acc[cc*4+3]);
      __syncthreads();
      {
        int c = tid>>6, b = tid&63; float s = 0.f;
        #pragma unroll
        for (int w16=0; w16<NWAVE; ++w16) s += PART[(w16*16 + c)*PSTR + b];
        GRED[c*64 + b] = s;
      }
      __syncthreads();
      if (tid < 256){
        int u = tid>>6, b = tid&63, j = 4*q2 + u;
        float gi = GRED[( 0+u)*64+b] + BS[ 0+u];
        float gf = GRED[( 4+u)*64+b] + BS[ 4+u];
        float gg = GRED[( 8+u)*64+b] + BS[ 8+u];
        float go = GRED[(12+u)*64+b] + BS[12+u];
        float c_ = sigm(gf)*CS[u*64+b] + sigm(gi)*tanhf(gg);
        float h_ = sigm(go)*tanhf(c_);
        CS[u*64+b] = c_;
        st_agent(&H2t[(size_t)(t2+1)*SLOT1 + j*64 + b], h_);
        if (t2 == TT-1){ outp[H1F_OFF + b*HIDN + j] = h_; outp[C1F_OFF + b*HIDN + j] = c_; }
      }
      __syncthreads();                       // drain publish
      if (tid == 0) arrive(&cnts[CHI(t2, q2>>3)]);
    }
  } else {
    // ================= WINDOW BLOCK (2 batches) =================
    const int wb = p - NH1 - NH2;
    const int b0 = wb * WBAT;
    float* WWT = SM;          float* ONE = SM + 13200;
    float* H1S = SM + 20880;  float* TMS = SM + 22080;
    float* PW  = SM + 22208;  float* KAP = SM + 22272;
    float* PHI = SM + 22304;

    for (int idx = tid; idx < 30*400; idx += THR){
      int j = idx/400, k = idx - j*400;
      WWT[k*33 + j] = Wwin[idx];
    }
    for (int idx = tid; idx < WBAT*UU*DD; idx += THR) ONE[idx] = onehots[b0*(UU*DD) + idx];
    if (tid < WBAT*UU) TMS[tid] = tmask[b0*UU + tid];
    if (tid < WBAT*16) KAP[tid] = 0.f;
    __syncthreads();

    for (int i = 0; i < TT; ++i){
      if (tid < 13) spin_ge(&cnts[CAI(i, tid)], tgtn(i, tid==12?4:8));
      asm volatile("" ::: "memory");
      __syncthreads();
      const float* __restrict__ H1now = H1t + (size_t)(i+1)*SLOT1;
      if (tid < 800){
        int bb = tid / 400, k = tid - bb*400;
        H1S[k*3 + bb] = H1now[k*64 + b0 + bb];
      }
      __syncthreads();
      if (tid < 960){
        int ks = tid & 15, pair = tid >> 4;
        int b = pair / 30, j = pair - b*30;
        float s = 0.f;
        #pragma unroll
        for (int kk = 0; kk < 25; ++kk){
          int k = ks*25 + kk;
          s = fmaf(H1S[k*3 + b], WWT[k*33 + j], s);
        }
        s += __shfl_down(s, 8, 16);
        s += __shfl_down(s, 4, 16);
        s += __shfl_down(s, 2, 16);
        s += __shfl_down(s, 1, 16);
        if (ks == 0) PW[b*32 + j] = expf(s + bwin[j]);
      }
      __syncthreads();
      if (tid < WBAT*KK){
        int b = tid/KK, k = tid - b*KK;
        KAP[b*16 + k] += PW[b*32 + 20 + k];
      }
      __syncthreads();
      if (tid < WBAT*UU){
        int b = tid >> 6, u = tid & 63;
        float uf = (float)u, s = 0.f;
        #pragma unroll
        for (int q = 0; q < KK; ++q){
          float d = KAP[b*16 + q] - uf;
          s = fmaf(PW[b*32 + q], expf(-PW[b*32 + 10 + q]*d*d), s);
        }
        s *= TMS[b*64 + u];
        PHI[b*64 + u] = s;
        if (i == TT-1) outp[PHI_OFF + (b0+b)*UU + u] = s;
      }
      __syncthreads();
      if (tid < WBAT*DD){
        int b = tid/DD, d = tid - b*DD;
        float s = 0.f;
        #pragma unroll 8
        for (int u = 0; u < UU; ++u) s = fmaf(PHI[b*64 + u], ONE[b*(UU*DD) + u*DD + d], s);
        st_agent(&Wh[(size_t)(i+1)*SLOTW + d*64 + b0 + b], s);  // publish w(i)
        if (i == TT-1) outp[WF_OFF + (b0+b)*DD + d] = s;
      }
      if (i == TT-1 && tid < WBAT*KK){
        int b = tid/KK, k = tid - b*KK;
        outp[KAPPA_OFF + (b0+b)*KK + k] = KAP[b*16 + k];
      }
      __syncthreads();                       // drain w publish
      if (tid == 0) arrive(&cnts[CWI(i, wb>>3)]);
    }
  }
}

// ---------- FC + heads: one block per timestep ----------
__global__ __launch_bounds__(128) void fc2_kernel(
    const float* __restrict__ H1t, const float* __restrict__ H2t,
    const float* __restrict__ WfcT, const float* __restrict__ bfc,
    float* __restrict__ outp)
{
  const int t   = blockIdx.x;
  const int tid = threadIdx.x;
  __shared__ float Xs[8][64];
  __shared__ float OUT[FCOUT][65];
  float acc[64];
  #pragma unroll
  for (int b=0;b<64;++b) acc[b]=0.f;
  const float* __restrict__ base1 = H1t + (size_t)(t+1)*SLOT1;
  const float* __restrict__ base2 = H2t + (size_t)(t+1)*SLOT1;

  for (int kb=0; kb<100; ++kb){
    __syncthreads();
    #pragma unroll
    for (int e=0;e<4;++e){
      int idx = e*128 + tid;
      int row = idx>>6, b = idx&63;
      int k = kb*8 + row;
      Xs[row][b] = (k<400) ? base1[k*64+b] : base2[(k-400)*64+b];
    }
    __syncthreads();
    if (tid < FCOUT){
      #pragma unroll
      for (int kk=0;kk<8;++kk){
        float wv = WfcT[(kb*8+kk)*FCOUT + tid];
        #pragma unroll
        for (int b4=0;b4<16;++b4){
          float4 xv = *(const float4*)&Xs[kk][b4*4];
          acc[b4*4+0] = fmaf(wv, xv.x, acc[b4*4+0]);
          acc[b4*4+1] = fmaf(wv, xv.y, acc[b4*4+1]);
          acc[b4*4+2] = fmaf(wv, xv.z, acc[b4*4+2]);
          acc[b4*4+3] = fmaf(wv, xv.w, acc[b4*4+3]);
        }
      }
    }
  }
  if (tid < FCOUT){
    float bj = bfc[tid];
    #pragma unroll
    for (int b=0;b<64;++b) OUT[tid][b] = acc[b] + bj;
  }
  __syncthreads();
  if (tid < 64){
    const int b = tid;
    const size_t pos = (size_t)b*TT + t;
    for (int j=0;j<40;++j) outp[MU_OFF  + pos*40 + j] = OUT[j][b];
    for (int j=0;j<40;++j) outp[SIG_OFF + pos*40 + j] = OUT[40+j][b];
    float m = -1e30f;
    for (int q=0;q<20;++q) m = fmaxf(m, OUT[80+q][b]);
    float e[20], s=0.f;
    for (int q=0;q<20;++q){ e[q]=expf(OUT[80+q][b]-m); s+=e[q]; }
    float inv = 1.f/s;
    for (int q=0;q<20;++q) outp[PI_OFF  + pos*20 + q] = e[q]*inv;
    for (int q=0;q<20;++q) outp[RHO_OFF + pos*20 + q] = tanhf(OUT[100+q][b]);
    outp[EOS_OFF + pos] = 1.0f/(1.0f + expf(OUT[120][b]));
  }
}

extern "C" void kernel_launch(void* const* d_in, const int* in_sizes, int n_in,
                              void* d_out, int out_size, void* d_ws, size_t ws_size,
                              hipStream_t stream){
  (void)in_sizes; (void)n_in; (void)out_size; (void)ws_size;
  const float* strokes = (const float*)d_in[0];
  const float* onehots = (const float*)d_in[1];
  const float* tmask   = (const float*)d_in[2];
  const float* Wih1    = (const float*)d_in[3];
  const float* Whh1    = (const float*)d_in[4];
  const float* b1      = (const float*)d_in[5];
  const float* Wwin    = (const float*)d_in[6];
  const float* bwin    = (const float*)d_in[7];
  const float* Wih2    = (const float*)d_in[8];
  const float* Whh2    = (const float*)d_in[9];
  const float* b2      = (const float*)d_in[10];
  const float* Wfc     = (const float*)d_in[11];
  const float* bfc     = (const float*)d_in[12];

  float* ws    = (float*)d_ws;
  float* outp  = (float*)d_out;
  float* H1t   = ws + WS_H1T;
  float* H2t   = ws + WS_H2T;
  float* Wh    = ws + WS_WHT;
  float* XST   = ws + WS_XST;
  float* WALL1 = ws + WS_WALL1;
  float* WALL2 = ws + WS_WALL2;
  float* WfcT  = ws + WS_WFCT;
  int*   cnts  = (int*)(ws + WS_CNT);

  hipLaunchKernelGGL(prep_init, dim3((TT*3*64 + 255)/256), dim3(256), 0, stream,
                     onehots, strokes, H1t, H2t, Wh, XST, cnts);
  hipLaunchKernelGGL(prep_wall, dim3((2121600 + 255)/256), dim3(256), 0, stream,
                     Wih1, Whh1, Wih2, Whh2, WALL1, WALL2);
  hipLaunchKernelGGL(prep_wfc, dim3((FCIN*FCOUT + 255)/256), dim3(256), 0, stream,
                     Wfc, WfcT);

  hipLaunchKernelGGL(recurrent_kernel, dim3(TOTB), dim3(THR), 0, stream,
                     Wwin, bwin, b1, b2, tmask, onehots, WALL1, WALL2,
                     H1t, H2t, Wh, XST, cnts, outp);

  hipLaunchKernelGGL(fc2_kernel, dim3(TT), dim3(128), 0, stream,
                     H1t, H2t, WfcT, bfc, outp);
}